// Round 12
// baseline (621.737 us; speedup 1.0000x reference)
//
#include <hip/hip_runtime.h>
#include <math.h>

#define D 256
#define NHD 8
#define HDIM 32
#define NPTS 4
#define NLAY 6
#define FFD 1024
#define BSZ 4
#define NSRC 9216
#define NQ 300
#define NROWS (BSZ*NQ)      // 1200
#define NVROWS (BSZ*NSRC)   // 36864
#define CCHK 256            // colsum chunks per batch (36 rows each)
#define VSTRIDE 1536        // value6 row stride (6 layers x 256)
#define LNEPS 1e-5f

typedef __attribute__((ext_vector_type(8))) short short8v;
typedef __attribute__((ext_vector_type(4))) float f32x4;

// async global->LDS, 16B per lane; dest = wave-uniform base + lane*16
#define GLOAD_LDS(g, l) __builtin_amdgcn_global_load_lds( \
    (const __attribute__((address_space(1))) void*)(g), \
    (__attribute__((address_space(3))) void*)(l), 16, 0, 0)

__device__ __forceinline__ unsigned short f2bf(float f){
  unsigned u = __float_as_uint(f);
  unsigned r = (u + 0x7FFFu + ((u>>16)&1u)) >> 16;
  return (unsigned short)r;
}
__device__ __forceinline__ float bf2f(unsigned short u){
  return __uint_as_float(((unsigned)u)<<16);
}

// ---------------- reduction helpers ----------------
__device__ __forceinline__ float wred_sum(float v){
#pragma unroll
  for(int o=32;o>=1;o>>=1) v += __shfl_xor(v,o,64);
  return v;
}
__device__ __forceinline__ float bred_sum(float v, float* s){
  v = wred_sum(v);
  int lane = threadIdx.x & 63, wid = threadIdx.x >> 6;
  if(lane==0) s[wid]=v;
  __syncthreads();
  float r = s[0]+s[1]+s[2]+s[3];
  __syncthreads();
  return r;
}

// ---------------- gating front-end ----------------
__global__ void colsum_partial(const float* __restrict__ aps, const float* __restrict__ dvs,
                               float* __restrict__ pA, float* __restrict__ pD){
  __shared__ float4 sA[4][64]; __shared__ float4 sD[4][64];
  int blk = blockIdx.x; int b = blk / CCHK; int c = blk % CCHK;
  int t = threadIdx.x; int cl = t & 63; int rg = t >> 6;
  const int rows = NSRC / CCHK;   // 36
  size_t base = ((size_t)b*NSRC + (size_t)c*rows)*D + cl*4;
  float4 sa = make_float4(0.f,0.f,0.f,0.f), sd = sa;
  for(int r=rg; r<rows; r+=4){
    float4 va = *(const float4*)(aps + base + (size_t)r*D);
    float4 vd = *(const float4*)(dvs + base + (size_t)r*D);
    sa.x+=va.x; sa.y+=va.y; sa.z+=va.z; sa.w+=va.w;
    sd.x+=vd.x; sd.y+=vd.y; sd.z+=vd.z; sd.w+=vd.w;
  }
  sA[rg][cl]=sa; sD[rg][cl]=sd;
  __syncthreads();
  if(t < 64){
    float4 r0=sA[0][t],r1=sA[1][t],r2=sA[2][t],r3=sA[3][t];
    float4 o; o.x=r0.x+r1.x+r2.x+r3.x; o.y=r0.y+r1.y+r2.y+r3.y;
    o.z=r0.z+r1.z+r2.z+r3.z; o.w=r0.w+r1.w+r2.w+r3.w;
    *(float4*)(pA + ((size_t)b*CCHK+c)*D + t*4) = o;
  } else if(t < 128){
    int u=t-64;
    float4 r0=sD[0][u],r1=sD[1][u],r2=sD[2][u],r3=sD[3][u];
    float4 o; o.x=r0.x+r1.x+r2.x+r3.x; o.y=r0.y+r1.y+r2.y+r3.y;
    o.z=r0.z+r1.z+r2.z+r3.z; o.w=r0.w+r1.w+r2.w+r3.w;
    *(float4*)(pD + ((size_t)b*CCHK+c)*D + u*4) = o;
  }
}

// s2 = colsum@W2 + N*b2 ; c = b1.s2   — one block per (b,modality)
__global__ void gate_s2(const float* __restrict__ pA, const float* __restrict__ pD,
                        const float* __restrict__ w2a, const float* __restrict__ b2a,
                        const float* __restrict__ w2d, const float* __restrict__ b2d,
                        const float* __restrict__ b1a, const float* __restrict__ b1d,
                        float* __restrict__ s2, float* __restrict__ cAB){
  __shared__ float sums[D]; __shared__ float red[4];
  int blk = blockIdx.x; int b = blk>>1; int mod = blk&1;
  int t = threadIdx.x;
  const float* pX = mod? pD : pA;
  const float* w2 = mod? w2d : w2a;
  const float* b2 = mod? b2d : b2a;
  const float* b1 = mod? b1d : b1a;
  float s=0.f;
  for(int c=0;c<CCHK;++c) s += pX[((size_t)b*CCHK+c)*D+t];
  sums[t]=s; __syncthreads();
  float v=0.f;
  for(int i=0;i<D;++i) v += sums[i]*w2[(size_t)i*D+t];
  v += (float)NSRC * b2[t];
  s2[(size_t)blk*D + t] = v;
  float c = bred_sum(b1[t]*v, red);
  if(t==0) cAB[mod*BSZ + b] = c;
}

// t = W1 @ s2 — one wave per output element (2048 waves)
__global__ void gate_t(const float* __restrict__ w1a, const float* __restrict__ w1d,
                       const float* __restrict__ s2,
                       float* __restrict__ tA, float* __restrict__ tD){
  int gw = blockIdx.x*4 + (threadIdx.x>>6);
  int lane = threadIdx.x & 63;
  int i = gw & 255; int bm = gw >> 8;      // bm = b*2+mod
  int mod = bm & 1, b = bm >> 1;
  const float* w1 = mod? w1d : w1a;
  const float* s2v = s2 + (size_t)bm*D;
  float4 wv = *(const float4*)(w1 + (size_t)i*D + lane*4);
  float4 sv = *(const float4*)(s2v + lane*4);
  float d = wv.x*sv.x + wv.y*sv.y + wv.z*sv.z + wv.w*sv.w;
  d = wred_sum(d);
  if(lane==0){
    if(mod) tD[b*D+i] = d; else tA[b*D+i] = d;
  }
}

// per-row gate softmax + fused src (emits bf16)
__global__ void gate_src(const float* __restrict__ aps, const float* __restrict__ dvs,
                         const float* __restrict__ tA, const float* __restrict__ tD,
                         const float* __restrict__ cAB, unsigned short* __restrict__ srcb){
  int w = threadIdx.x >> 6, lane = threadIdx.x & 63;
  size_t row = (size_t)blockIdx.x*4 + w;
  int b = (int)(row / NSRC);
  const float4* ap = (const float4*)(aps + row*D);
  const float4* dp = (const float4*)(dvs + row*D);
  const float4* tap = (const float4*)(tA + (size_t)b*D);
  const float4* tdp = (const float4*)(tD + (size_t)b*D);
  float4 a = ap[lane], dd = dp[lane], ta = tap[lane], td = tdp[lane];
  float ga = a.x*ta.x + a.y*ta.y + a.z*ta.z + a.w*ta.w;
  float gd = dd.x*td.x + dd.y*td.y + dd.z*td.z + dd.w*td.w;
  ga = (wred_sum(ga) + cAB[b]) * 0.0625f;       // 1/sqrt(256)
  gd = (wred_sum(gd) + cAB[BSZ+b]) * 0.0625f;
  float m = fmaxf(ga,gd);
  float ea = expf(ga-m), ed = expf(gd-m);
  float inv = 1.f/(ea+ed);
  float wa = ea*inv, wd = ed*inv;
  ushort4 o;
  o.x = f2bf(wa*a.x + wd*dd.x); o.y = f2bf(wa*a.y + wd*dd.y);
  o.z = f2bf(wa*a.z + wd*dd.z); o.w = f2bf(wa*a.w + wd*dd.w);
  ((ushort4*)(srcb + row*D))[lane] = o;
}

// all weight transpose+convert in one launch: Bt[l][n][k] = bf16(W[l][k][n])
__global__ void wconv_all(const float* __restrict__ valw, const float* __restrict__ saqkvw,
                          const float* __restrict__ saoutw, const float* __restrict__ coutw,
                          const float* __restrict__ ffw1, const float* __restrict__ ffw2,
                          unsigned short* __restrict__ valT, unsigned short* __restrict__ qkvT,
                          unsigned short* __restrict__ saoutT, unsigned short* __restrict__ coutT,
                          unsigned short* __restrict__ ff1T, unsigned short* __restrict__ ff2T){
  __shared__ float tile[32][33];
  int bid = blockIdx.x;
  const float* W; unsigned short* Bt; int K, N, rel;
  if(bid < 384)      { W=valw;   Bt=valT;   K=256;  N=256;  rel=bid; }
  else if(bid < 1536){ W=saqkvw; Bt=qkvT;   K=256;  N=768;  rel=bid-384; }
  else if(bid < 1920){ W=saoutw; Bt=saoutT; K=256;  N=256;  rel=bid-1536; }
  else if(bid < 2304){ W=coutw;  Bt=coutT;  K=256;  N=256;  rel=bid-1920; }
  else if(bid < 3840){ W=ffw1;   Bt=ff1T;   K=256;  N=1024; rel=bid-2304; }
  else               { W=ffw2;   Bt=ff2T;   K=1024; N=256;  rel=bid-3840; }
  int nk = K>>5, nn = N>>5, tpl = nk*nn;
  int l = rel/tpl, rem = rel%tpl;
  int tk = rem % nk, tn = rem / nk;
  int tx = threadIdx.x & 31, ty = threadIdx.x >> 5;
  const float* Wl = W + (size_t)l*K*N;
  unsigned short* Btl = Bt + (size_t)l*N*K;
#pragma unroll
  for(int i=0;i<4;++i)
    tile[ty+i*8][tx] = Wl[(size_t)(tk*32+ty+i*8)*N + tn*32+tx];
  __syncthreads();
#pragma unroll
  for(int i=0;i<4;++i)
    Btl[(size_t)(tn*32+ty+i*8)*K + tk*32+tx] = f2bf(tile[tx][ty+i*8]);
}

__global__ void init_out_ref(const float* __restrict__ qe, const float* __restrict__ refw,
                             const float* __restrict__ refb,
                             float* __restrict__ outb, unsigned short* __restrict__ out_bf,
                             unsigned short* __restrict__ outpos_bf,
                             float* __restrict__ refp, float* __restrict__ dout){
  __shared__ float red[4];
  int q = blockIdx.x, t = threadIdx.x;
  float pos = qe[(size_t)q*2*D + t];
  float tgt = qe[(size_t)q*2*D + D + t];
  unsigned short tb = f2bf(tgt), tpb = f2bf(tgt+pos);
  for(int b=0;b<BSZ;++b){
    outb[((size_t)b*NQ+q)*D + t] = tgt;
    out_bf[((size_t)b*NQ+q)*D + t] = tb;
    outpos_bf[((size_t)b*NQ+q)*D + t] = tpb;
  }
  float d0 = bred_sum(pos*refw[t*2+0], red);
  float d1 = bred_sum(pos*refw[t*2+1], red);
  if(t<2){
    float dot = (t==0? d0 : d1) + refb[t];
    float r = 1.f/(1.f+expf(-dot));
    refp[q*2+t] = r;
    const size_t o1 = (size_t)BSZ*NQ*D;
    const size_t o2 = o1 + (size_t)BSZ*NQ*2;
    for(int b=0;b<BSZ;++b){
      dout[o1 + (b*NQ+q)*2 + t] = r;
      dout[o2 + (b*NQ+q)*2 + t] = r;
    }
  }
}

// ---- unified bf16 MFMA GEMM (M-chain), 64x64 tile, FULL-K (BK=256) staging --
__global__ __launch_bounds__(256) void gemmb(
    const unsigned short* __restrict__ A,   // [M][K] bf16
    const unsigned short* __restrict__ A2,
    int ncut,
    const unsigned short* __restrict__ Bt,  // [N][K] bf16
    const float* __restrict__ bias,
    float* __restrict__ Cf, unsigned short* __restrict__ Cb,
    int M, int K, int N, int relu){
  __shared__ unsigned short As[64][256];
  __shared__ unsigned short Bs[64][256];
  int n0 = blockIdx.x*64, m0 = blockIdx.y*64;
  const unsigned short* Asrc = (A2 && n0 >= ncut) ? A2 : A;
  int t = threadIdx.x, wave = t>>6, lane = t&63;
  int wm = (wave>>1)*32, wn = (wave&1)*32;
  int hi = lane>>4, lo = lane&15;
  int lrow2 = lane>>5, lslot = lane&31;
  f32x4 acc[2][2];
#pragma unroll
  for(int i=0;i<2;++i)
#pragma unroll
    for(int j=0;j<2;++j)
#pragma unroll
      for(int r=0;r<4;++r) acc[i][j][r]=0.f;

  for(int k0=0;k0<K;k0+=256){
#pragma unroll
    for(int i=0;i<8;++i){
      int rt = wave*16 + 2*i + lrow2;          // tile row this lane feeds
      int col = ((lslot ^ (rt&7)))*8;          // pre-swizzled source slot
      int ga = m0+rt; if(ga >= M) ga = M-1;
      GLOAD_LDS(Asrc + (size_t)ga*K + k0 + col, &As[wave*16 + 2*i][0]);
      GLOAD_LDS(Bt + (size_t)(n0+rt)*K + k0 + col, &Bs[wave*16 + 2*i][0]);
    }
    __syncthreads();
#pragma unroll
    for(int kk=0;kk<8;++kk){
      int ps = (((kk*4+hi) ^ (lo&7)))*8;       // physical slot (elements)
      short8v a0 = *(short8v*)&As[wm+lo][ps];
      short8v a1 = *(short8v*)&As[wm+16+lo][ps];
      short8v b0 = *(short8v*)&Bs[wn+lo][ps];
      short8v b1 = *(short8v*)&Bs[wn+16+lo][ps];
      acc[0][0] = __builtin_amdgcn_mfma_f32_16x16x32_bf16(a0,b0,acc[0][0],0,0,0);
      acc[0][1] = __builtin_amdgcn_mfma_f32_16x16x32_bf16(a0,b1,acc[0][1],0,0,0);
      acc[1][0] = __builtin_amdgcn_mfma_f32_16x16x32_bf16(a1,b0,acc[1][0],0,0,0);
      acc[1][1] = __builtin_amdgcn_mfma_f32_16x16x32_bf16(a1,b1,acc[1][1],0,0,0);
    }
    if(k0 + 256 < K) __syncthreads();
  }
#pragma unroll
  for(int mf=0;mf<2;++mf){
#pragma unroll
    for(int nf=0;nf<2;++nf){
      int col = n0 + wn + nf*16 + lo;
      float bv = bias[col];
#pragma unroll
      for(int r=0;r<4;++r){
        int row = m0 + wm + mf*16 + hi*4 + r;
        if(row < M){
          float v = acc[mf][nf][r] + bv;
          if(relu) v = fmaxf(v, 0.f);
          if(Cf) Cf[(size_t)row*N+col] = v;
          if(Cb) Cb[(size_t)row*N+col] = f2bf(v);
        }
      }
    }
  }
}

// ------- bf16 MFMA value GEMM for ALL layers: [36864,256]@[256,1536] --------
// linear LDS + global_load_lds + XCD chunk swizzle + slot XOR bank swizzle
// + LDS-transpose epilogue for coalesced 16B/lane stores
__global__ __launch_bounds__(256) void mfma_value6(
    const unsigned short* __restrict__ Abf,   // [M][256] bf16
    const unsigned short* __restrict__ Bt,    // [1536][256] bf16 (all layers)
    const float* __restrict__ bias,           // [1536] (valb flat)
    const unsigned char* __restrict__ rowmask,
    unsigned short* __restrict__ C){          // [M][1536] bf16
  __shared__ union {
    struct { unsigned short As[128][32]; unsigned short Bs[128][32]; } st;
    unsigned short ob[128][132];              // padded output staging (33 KB)
  } U;
  // bijective XCD swizzle: 3456 blocks = 8 x 432; each XCD gets 36 m-panels x 12 n
  int id = blockIdx.x;
  int swz = (id & 7)*432 + (id >> 3);
  int m0 = (swz/12)*128, n0 = (swz%12)*128;
  int t = threadIdx.x;
  int wave = t>>6, lane = t&63;
  int wm = (wave>>1)*64, wn = (wave&1)*64;
  f32x4 acc[4][4];
#pragma unroll
  for(int i=0;i<4;++i)
#pragma unroll
    for(int j=0;j<4;++j)
#pragma unroll
      for(int r=0;r<4;++r) acc[i][j][r]=0.f;

  // staging with pre-swizzled global column: phys slot (l&3) holds logical
  // slot (l&3)^((row>>1)&3); row = wave*32 + (l>>2)  (and +16 variant)
  int colx = ((lane&3) ^ ((lane>>3)&3)) * 8;
  const unsigned short* Ag = Abf + (size_t)(m0 + wave*32 + (lane>>2))*256 + colx;
  const unsigned short* Bg = Bt  + (size_t)(n0 + wave*32 + (lane>>2))*256 + colx;
  unsigned short* Al0 = &U.st.As[wave*32][0];
  unsigned short* Al1 = &U.st.As[wave*32+16][0];
  unsigned short* Bl0 = &U.st.Bs[wave*32][0];
  unsigned short* Bl1 = &U.st.Bs[wave*32+16][0];

  int hi = lane>>4, lo = lane&15;
  int sx = (hi ^ ((lo>>1)&3)) * 8;   // read-side physical slot (elements)

  for(int k0=0;k0<256;k0+=32){
    GLOAD_LDS(Ag + k0,           Al0);
    GLOAD_LDS(Ag + k0 + 16*256,  Al1);
    GLOAD_LDS(Bg + k0,           Bl0);
    GLOAD_LDS(Bg + k0 + 16*256,  Bl1);
    __syncthreads();
    short8v a[4], bb[4];
#pragma unroll
    for(int mf=0;mf<4;++mf) a[mf]  = *(short8v*)&U.st.As[wm+mf*16+lo][sx];
#pragma unroll
    for(int nf=0;nf<4;++nf) bb[nf] = *(short8v*)&U.st.Bs[wn+nf*16+lo][sx];
#pragma unroll
    for(int mf=0;mf<4;++mf)
#pragma unroll
      for(int nf=0;nf<4;++nf)
        acc[mf][nf] = __builtin_amdgcn_mfma_f32_16x16x32_bf16(a[mf], bb[nf], acc[mf][nf], 0,0,0);
    __syncthreads();
  }
  // ---- epilogue: stage tile in LDS, then coalesced 16B/lane stores ----
#pragma unroll
  for(int mf=0;mf<4;++mf){
#pragma unroll
    for(int nf=0;nf<4;++nf){
#pragma unroll
      for(int r=0;r<4;++r){
        int rl = wm + mf*16 + hi*4 + r;
        int cl = wn + nf*16 + lo;
        float v = acc[mf][nf][r] + bias[n0+cl];
        if(rowmask[m0+rl]) v = 0.f;
        U.ob[rl][cl] = f2bf(v);
      }
    }
  }
  __syncthreads();
#pragma unroll
  for(int it=0; it<8; ++it){
    int row = it*16 + (t>>4);
    int c0 = (t&15)*8;
    *(uint4*)(C + (size_t)(m0+row)*VSTRIDE + n0 + c0) = *(uint4*)&U.ob[row][c0];
  }
}

// ---------------- MFMA self attention: block = (b,h) x 64-row Q tile --------
__global__ __launch_bounds__(256) void self_attn_mfma(
    const unsigned short* __restrict__ qkvh, // [1200][768] bf16 (q|k|v)
    unsigned short* __restrict__ sa){        // [1200][256] bf16
  __shared__ unsigned short P[64][328];
  __shared__ unsigned short Vt[32][328];
  int blk = blockIdx.x;
  int qt = blk % 5; int bh = blk / 5; int h = bh % NHD; int b = bh / NHD;
  int t = threadIdx.x, wv = t>>6, lane = t&63;
  int hi = lane>>4, lo = lane&15;
  {
    int c = t & 31, rb = t >> 5;
    for(int r = rb; r < 320; r += 8){
      unsigned short v = 0;
      if(r < 300) v = qkvh[(size_t)(b*300+r)*768 + 512 + h*32 + c];
      Vt[c][r] = v;
    }
  }
  __syncthreads();
  int m0 = qt*64 + wv*16;
  int qr = m0 + lo; if(qr > 299) qr = 299;
  short8v aq = *(const short8v*)(qkvh + (size_t)(b*300+qr)*768 + h*32 + hi*8);
  f32x4 s[19];
#pragma unroll
  for(int nt=0; nt<19; ++nt){
    int kr = nt*16 + lo; if(kr > 299) kr = 299;
    short8v bk = *(const short8v*)(qkvh + (size_t)(b*300+kr)*768 + 256 + h*32 + hi*8);
    f32x4 z; z[0]=0.f; z[1]=0.f; z[2]=0.f; z[3]=0.f;
    s[nt] = __builtin_amdgcn_mfma_f32_16x16x32_bf16(aq, bk, z, 0,0,0);
  }
  const float kSc = 0.25506009837f;   // (1/sqrt(32)) * log2(e)
  float inv[4];
#pragma unroll
  for(int ri=0; ri<4; ++ri){
    float m = -1e30f;
#pragma unroll
    for(int nt=0; nt<19; ++nt){
      if(nt*16+lo < 300) m = fmaxf(m, s[nt][ri]);
    }
#pragma unroll
    for(int o=8;o>=1;o>>=1) m = fmaxf(m, __shfl_xor(m,o,64));
    float sum = 0.f;
#pragma unroll
    for(int nt=0; nt<19; ++nt){
      float p = 0.f;
      if(nt*16+lo < 300) p = exp2f((s[nt][ri]-m)*kSc);
      sum += p;
      P[wv*16 + hi*4 + ri][nt*16 + lo] = f2bf(p);
    }
    P[wv*16 + hi*4 + ri][304 + lo] = 0;
#pragma unroll
    for(int o=8;o>=1;o>>=1) sum += __shfl_xor(sum,o,64);
    inv[ri] = 1.f/sum;
  }
  f32x4 o0, o1;
#pragma unroll
  for(int r=0;r<4;++r){ o0[r]=0.f; o1[r]=0.f; }
#pragma unroll
  for(int kt=0; kt<10; ++kt){
    short8v ap = *(short8v*)&P[wv*16 + lo][kt*32 + hi*8];
    short8v b0 = *(short8v*)&Vt[lo][kt*32 + hi*8];
    short8v b1 = *(short8v*)&Vt[16+lo][kt*32 + hi*8];
    o0 = __builtin_amdgcn_mfma_f32_16x16x32_bf16(ap, b0, o0, 0,0,0);
    o1 = __builtin_amdgcn_mfma_f32_16x16x32_bf16(ap, b1, o1, 0,0,0);
  }
#pragma unroll
  for(int ri=0; ri<4; ++ri){
    int r = m0 + hi*4 + ri;
    if(r < 300){
      size_t base = (size_t)(b*300+r)*256 + h*32;
      sa[base + lo]      = f2bf(o0[ri]*inv[ri]);
      sa[base + 16 + lo] = f2bf(o1[ri]*inv[ri]);
    }
  }
}

// ------- residual + layernorm, one ROW per WAVE, float4 loads, no LDS -------
__global__ void residual_ln(const float* __restrict__ base, const float* __restrict__ delta,
                            const float* __restrict__ lw, const float* __restrict__ lb,
                            float* __restrict__ dstf, unsigned short* __restrict__ dstb,
                            unsigned short* __restrict__ dstp, const float* __restrict__ qe){
  int w = threadIdx.x >> 6, lane = threadIdx.x & 63;
  size_t row = (size_t)blockIdx.x*4 + w;
  float4 bv = ((const float4*)(base + row*D))[lane];
  float4 dv = ((const float4*)(delta + row*D))[lane];
  float4 v; v.x=bv.x+dv.x; v.y=bv.y+dv.y; v.z=bv.z+dv.z; v.w=bv.w+dv.w;
  float s = wred_sum(v.x+v.y+v.z+v.w);
  float mean = s * (1.f/D);
  float4 c; c.x=v.x-mean; c.y=v.y-mean; c.z=v.z-mean; c.w=v.w-mean;
  float vs = wred_sum(c.x*c.x + c.y*c.y + c.z*c.z + c.w*c.w);
  float inv = rsqrtf(vs*(1.f/D) + LNEPS);
  float4 wv = ((const float4*)lw)[lane];
  float4 lbv = ((const float4*)lb)[lane];
  float4 y; y.x=c.x*inv*wv.x+lbv.x; y.y=c.y*inv*wv.y+lbv.y;
  y.z=c.z*inv*wv.z+lbv.z; y.w=c.w*inv*wv.w+lbv.w;
  ((float4*)(dstf + row*D))[lane] = y;
  if(dstb){
    ushort4 o; o.x=f2bf(y.x); o.y=f2bf(y.y); o.z=f2bf(y.z); o.w=f2bf(y.w);
    ((ushort4*)(dstb + row*D))[lane] = o;
  }
  if(dstp){
    int q = (int)(row % NQ);
    float4 qv = ((const float4*)(qe + (size_t)q*2*D))[lane];
    ushort4 o; o.x=f2bf(y.x+qv.x); o.y=f2bf(y.y+qv.y);
    o.z=f2bf(y.z+qv.z); o.w=f2bf(y.w+qv.w);
    ((ushort4*)(dstp + row*D))[lane] = o;
  }
}

// ---- fused: residual+LN (post-saout) + deformable cross-attn ---------------
__global__ void deform_attn_ln(const float* __restrict__ base, const float* __restrict__ delta,
                               const float* __restrict__ lnw, const float* __restrict__ lnb,
                               float* __restrict__ outb,      // LN result written back
                               const float* __restrict__ qe,
                               const float* __restrict__ offw, const float* __restrict__ offb,
                               const float* __restrict__ attnw, const float* __restrict__ attnb,
                               const unsigned short* __restrict__ value, const float* __restrict__ refp,
                               const float* __restrict__ vr, const int* __restrict__ sshape,
                               unsigned short* __restrict__ ca){
  __shared__ float qrow[D];
  __shared__ float part[96][2];
  __shared__ float proj[96];
  __shared__ float red[4];
  int row = blockIdx.x; int b = row / NQ; int q = row % NQ;
  int t = threadIdx.x;
  // residual + LN (per-row, full row in block)
  float v = base[(size_t)row*D+t] + delta[(size_t)row*D+t];
  float mean = bred_sum(v, red) * (1.f/D);
  float c = v - mean;
  float var = bred_sum(c*c, red) * (1.f/D);
  float y = c * rsqrtf(var + LNEPS) * lnw[t] + lnb[t];
  outb[(size_t)row*D+t] = y;
  qrow[t] = y + qe[(size_t)q*2*D + t];
  __syncthreads();
  if(t < 192){
    int col = t >> 1, half = t & 1;
    float acc = 0.f;
    if(col < 64){
      const float* W = offw;
      for(int k=half*128; k<half*128+128; ++k) acc += qrow[k]*W[(size_t)k*64 + col];
    } else {
      const float* W = attnw; int cc = col-64;
      for(int k=half*128; k<half*128+128; ++k) acc += qrow[k]*W[(size_t)k*32 + cc];
    }
    part[col][half] = acc;
  }
  __syncthreads();
  if(t < 96) proj[t] = part[t][0] + part[t][1] + (t<64 ? offb[t] : attnb[t-64]);
  __syncthreads();

  int h = t>>5, hd = t&31;
  float Hf = (float)sshape[0], Wf = (float)sshape[1];
  int Ws = sshape[1];
  float rx = refp[q*2+0] * vr[b*2+0];
  float ry = refp[q*2+1] * vr[b*2+1];
  const float* lg = &proj[64 + h*4];
  float m = fmaxf(fmaxf(lg[0],lg[1]),fmaxf(lg[2],lg[3]));
  float e[4]; float esum=0.f;
#pragma unroll
  for(int p=0;p<4;++p){ e[p]=expf(lg[p]-m); esum+=e[p]; }
  float einv = 1.f/esum;
  const float* ofr = &proj[h*8];
  const unsigned short* vbase = value + ((size_t)b*NSRC)*VSTRIDE + h*HDIM + hd;
  float acc = 0.f;
#pragma unroll
  for(int p=0;p<NPTS;++p){
    float lx = rx + ofr[p*2+0]/Wf;
    float ly = ry + ofr[p*2+1]/Hf;
    float x = lx*Wf - 0.5f, y2 = ly*Hf - 0.5f;
    float x0 = floorf(x), y0 = floorf(y2);
    float wx = x-x0, wy = y2-y0;
    float sample = 0.f;
#pragma unroll
    for(int cy=0;cy<2;++cy){
#pragma unroll
      for(int cx=0;cx<2;++cx){
        float xi = x0+cx, yi = y0+cy;
        float wgt = (cx? wx : 1.f-wx) * (cy? wy : 1.f-wy);
        bool valid = (xi>=0.f)&&(xi<=Wf-1.f)&&(yi>=0.f)&&(yi<=Hf-1.f);
        if(valid){
          int idx = (int)fminf(fmaxf(yi,0.f),Hf-1.f)*Ws + (int)fminf(fmaxf(xi,0.f),Wf-1.f);
          sample += wgt * bf2f(vbase[(size_t)idx*VSTRIDE]);
        }
      }
    }
    acc += (e[p]*einv) * sample;
  }
  ca[(size_t)row*D + h*HDIM + hd] = f2bf(acc);
}

// ---------------- host ----------------
extern "C" void kernel_launch(void* const* d_in, const int* in_sizes, int n_in,
                              void* d_out, int out_size, void* d_ws, size_t ws_size,
                              hipStream_t stream){
  const float* aps=(const float*)d_in[0];
  const float* dvs=(const float*)d_in[1];
  const float* qe =(const float*)d_in[2];
  const float* vr =(const float*)d_in[3];
  const float* aps_w1=(const float*)d_in[4]; const float* aps_b1=(const float*)d_in[5];
  const float* aps_w2=(const float*)d_in[6]; const float* aps_b2=(const float*)d_in[7];
  const float* dvs_w1=(const float*)d_in[8]; const float* dvs_b1=(const float*)d_in[9];
  const float* dvs_w2=(const float*)d_in[10]; const float* dvs_b2=(const float*)d_in[11];
  const float* ref_w=(const float*)d_in[12]; const float* ref_b=(const float*)d_in[13];
  const float* saqkvw=(const float*)d_in[14]; const float* saqkvb=(const float*)d_in[15];
  const float* saoutw=(const float*)d_in[16]; const float* saoutb=(const float*)d_in[17];
  const float* offw=(const float*)d_in[18]; const float* offb=(const float*)d_in[19];
  const float* attnw=(const float*)d_in[20]; const float* attnb=(const float*)d_in[21];
  const float* valw=(const float*)d_in[22]; const float* valb=(const float*)d_in[23];
  const float* coutw=(const float*)d_in[24]; const float* coutb=(const float*)d_in[25];
  const float* ln1w=(const float*)d_in[26]; const float* ln1b=(const float*)d_in[27];
  const float* ln2w=(const float*)d_in[28]; const float* ln2b=(const float*)d_in[29];
  const float* ln3w=(const float*)d_in[30]; const float* ln3b=(const float*)d_in[31];
  const float* ffw1=(const float*)d_in[32]; const float* ffb1=(const float*)d_in[33];
  const float* ffw2=(const float*)d_in[34]; const float* ffb2=(const float*)d_in[35];
  const unsigned char* mask=(const unsigned char*)d_in[36];
  const int* sshape=(const int*)d_in[37];
  float* out = (float*)d_out;

  char* wsb = (char*)d_ws;
  size_t o = 0;
  unsigned short* srcb   = (unsigned short*)(wsb+o); o += (size_t)NVROWS*D*2;
  unsigned short* valT   = (unsigned short*)(wsb+o); o += (size_t)NLAY*D*D*2;
  unsigned short* qkvT   = (unsigned short*)(wsb+o); o += (size_t)NLAY*3*D*D*2;
  unsigned short* saoutT = (unsigned short*)(wsb+o); o += (size_t)NLAY*D*D*2;
  unsigned short* coutT  = (unsigned short*)(wsb+o); o += (size_t)NLAY*D*D*2;
  unsigned short* ff1T   = (unsigned short*)(wsb+o); o += (size_t)NLAY*D*FFD*2;
  unsigned short* ff2T   = (unsigned short*)(wsb+o); o += (size_t)NLAY*FFD*D*2;
  unsigned short* value  = (unsigned short*)(wsb+o); o += (size_t)NVROWS*VSTRIDE*2;
  float* pA    = (float*)(wsb+o); o += (size_t)BSZ*CCHK*D*4;
  float* pD    = (float*)(wsb+o); o += (size_t)BSZ*CCHK*D*4;
  float* s2    = (float*)(wsb+o); o += 2*BSZ*D*4;
  float* tA    = (float*)(wsb+o); o += BSZ*D*4;
  float* tD    = (float*)(wsb+o); o += BSZ*D*4;
  float* cAB   = (float*)(wsb+o); o += 16*4;
  float* refp  = (float*)(wsb+o); o += NQ*2*4;
  float* outb  = (float*)(wsb+o); o += (size_t)NROWS*D*4;
  float* tmpb  = (float*)(wsb+o); o += (size_t)NROWS*D*4;
  unsigned short* out_bf    = (unsigned short*)(wsb+o); o += (size_t)NROWS*D*2;
  unsigned short* outpos_bf = (unsigned short*)(wsb+o); o += (size_t)NROWS*D*2;
  unsigned short* qkvh_bf   = (unsigned short*)(wsb+o); o += (size_t)NROWS*3*D*2;
  unsigned short* sa_bf     = (unsigned short*)(wsb+o); o += (size_t)NROWS*D*2;
  unsigned short* ca_bf     = (unsigned short*)(wsb+o); o += (size_t)NROWS*D*2;
  unsigned short* ffh_bf    = (unsigned short*)(wsb+o); o += (size_t)NROWS*FFD*2;

  // ---- prologue
  colsum_partial<<<BSZ*CCHK,256,0,stream>>>(aps,dvs,pA,pD);
  gate_s2<<<2*BSZ,256,0,stream>>>(pA,pD,aps_w2,aps_b2,dvs_w2,dvs_b2,aps_b1,dvs_b1,s2,cAB);
  gate_t<<<512,256,0,stream>>>(aps_w1,dvs_w1,s2,tA,tD);
  gate_src<<<NVROWS/4,256,0,stream>>>(aps,dvs,tA,tD,cAB,srcb);
  wconv_all<<<5376,256,0,stream>>>(valw,saqkvw,saoutw,coutw,ffw1,ffw2,
                                   valT,qkvT,saoutT,coutT,ff1T,ff2T);
  init_out_ref<<<NQ,256,0,stream>>>(qe,ref_w,ref_b,outb,out_bf,outpos_bf,refp,out);
  mfma_value6<<<(NVROWS/128)*(VSTRIDE/128),256,0,stream>>>(srcb, valT, valb, mask, value);

  dim3 gqkv(12,19), g256(4,19), gffu(16,19);

  for(int l=0;l<NLAY;++l){
    const unsigned short* qkvTl = qkvT + (size_t)l*3*D*D;
    const float* bqkv = saqkvb + (size_t)l*3*D;
    // self attention: q,k from out+qpos, v from out — one fused GEMM (N=768)
    gemmb<<<gqkv,256,0,stream>>>(outpos_bf, out_bf, 512, qkvTl, bqkv,
                                 nullptr, qkvh_bf, NROWS, D, 3*D, 0);
    self_attn_mfma<<<BSZ*NHD*5,256,0,stream>>>(qkvh_bf, sa_bf);
    gemmb<<<g256,256,0,stream>>>(sa_bf, nullptr, 0, saoutT+(size_t)l*D*D, saoutb+(size_t)l*D,
                                 tmpb, nullptr, NROWS, D, D, 0);

    // fused: residual+LN(ln2) + deformable cross attention
    deform_attn_ln<<<NROWS,256,0,stream>>>(outb, tmpb, ln2w+(size_t)l*D, ln2b+(size_t)l*D,
                                           outb, qe,
                                           offw+(size_t)l*D*64, offb+(size_t)l*64,
                                           attnw+(size_t)l*D*32, attnb+(size_t)l*32,
                                           value + (size_t)l*D, refp, vr, sshape, ca_bf);
    gemmb<<<g256,256,0,stream>>>(ca_bf, nullptr, 0, coutT+(size_t)l*D*D, coutb+(size_t)l*D,
                                 tmpb, nullptr, NROWS, D, D, 0);
    residual_ln<<<NROWS/4,256,0,stream>>>(outb,tmpb,ln1w+(size_t)l*D,ln1b+(size_t)l*D,
                                          outb,out_bf,nullptr,qe);

    // FFN
    gemmb<<<gffu,256,0,stream>>>(out_bf, nullptr, 0, ff1T+(size_t)l*D*FFD, ffb1+(size_t)l*FFD,
                                 nullptr, ffh_bf, NROWS, D, FFD, 1);
    gemmb<<<g256,256,0,stream>>>(ffh_bf, nullptr, 0, ff2T+(size_t)l*FFD*D, ffb2+(size_t)l*D,
                                 tmpb, nullptr, NROWS, FFD, D, 0);
    if(l==NLAY-1)
      residual_ln<<<NROWS/4,256,0,stream>>>(outb,tmpb,ln3w+(size_t)l*D,ln3b+(size_t)l*D,
                                            out,nullptr,nullptr,qe);
    else
      residual_ln<<<NROWS/4,256,0,stream>>>(outb,tmpb,ln3w+(size_t)l*D,ln3b+(size_t)l*D,
                                            outb,out_bf,outpos_bf,qe);
  }
}

// Round 13
// 616.475 us; speedup vs baseline: 1.0085x; 1.0085x over previous
//
#include <hip/hip_runtime.h>
#include <math.h>

#define D 256
#define NHD 8
#define HDIM 32
#define NPTS 4
#define NLAY 6
#define FFD 1024
#define BSZ 4
#define NSRC 9216
#define NQ 300
#define NROWS (BSZ*NQ)      // 1200
#define NVROWS (BSZ*NSRC)   // 36864
#define CCHK 256            // colsum chunks per batch (36 rows each)
#define VSTRIDE 1536        // value6 row stride (6 layers x 256)
#define LNEPS 1e-5f

typedef __attribute__((ext_vector_type(8))) short short8v;
typedef __attribute__((ext_vector_type(4))) float f32x4;

// async global->LDS, 16B per lane; dest = wave-uniform base + lane*16
#define GLOAD_LDS(g, l) __builtin_amdgcn_global_load_lds( \
    (const __attribute__((address_space(1))) void*)(g), \
    (__attribute__((address_space(3))) void*)(l), 16, 0, 0)

__device__ __forceinline__ unsigned short f2bf(float f){
  unsigned u = __float_as_uint(f);
  unsigned r = (u + 0x7FFFu + ((u>>16)&1u)) >> 16;
  return (unsigned short)r;
}
__device__ __forceinline__ float bf2f(unsigned short u){
  return __uint_as_float(((unsigned)u)<<16);
}

// ---------------- reduction helpers ----------------
__device__ __forceinline__ float wred_sum(float v){
#pragma unroll
  for(int o=32;o>=1;o>>=1) v += __shfl_xor(v,o,64);
  return v;
}
__device__ __forceinline__ float bred_sum(float v, float* s){
  v = wred_sum(v);
  int lane = threadIdx.x & 63, wid = threadIdx.x >> 6;
  if(lane==0) s[wid]=v;
  __syncthreads();
  float r = s[0]+s[1]+s[2]+s[3];
  __syncthreads();
  return r;
}

// ---------------- gating front-end ----------------
__global__ void colsum_partial(const float* __restrict__ aps, const float* __restrict__ dvs,
                               float* __restrict__ pA, float* __restrict__ pD){
  __shared__ float4 sA[4][64]; __shared__ float4 sD[4][64];
  int blk = blockIdx.x; int b = blk / CCHK; int c = blk % CCHK;
  int t = threadIdx.x; int cl = t & 63; int rg = t >> 6;
  const int rows = NSRC / CCHK;   // 36
  size_t base = ((size_t)b*NSRC + (size_t)c*rows)*D + cl*4;
  float4 sa = make_float4(0.f,0.f,0.f,0.f), sd = sa;
  for(int r=rg; r<rows; r+=4){
    float4 va = *(const float4*)(aps + base + (size_t)r*D);
    float4 vd = *(const float4*)(dvs + base + (size_t)r*D);
    sa.x+=va.x; sa.y+=va.y; sa.z+=va.z; sa.w+=va.w;
    sd.x+=vd.x; sd.y+=vd.y; sd.z+=vd.z; sd.w+=vd.w;
  }
  sA[rg][cl]=sa; sD[rg][cl]=sd;
  __syncthreads();
  if(t < 64){
    float4 r0=sA[0][t],r1=sA[1][t],r2=sA[2][t],r3=sA[3][t];
    float4 o; o.x=r0.x+r1.x+r2.x+r3.x; o.y=r0.y+r1.y+r2.y+r3.y;
    o.z=r0.z+r1.z+r2.z+r3.z; o.w=r0.w+r1.w+r2.w+r3.w;
    *(float4*)(pA + ((size_t)b*CCHK+c)*D + t*4) = o;
  } else if(t < 128){
    int u=t-64;
    float4 r0=sD[0][u],r1=sD[1][u],r2=sD[2][u],r3=sD[3][u];
    float4 o; o.x=r0.x+r1.x+r2.x+r3.x; o.y=r0.y+r1.y+r2.y+r3.y;
    o.z=r0.z+r1.z+r2.z+r3.z; o.w=r0.w+r1.w+r2.w+r3.w;
    *(float4*)(pD + ((size_t)b*CCHK+c)*D + u*4) = o;
  }
}

// s2 = colsum@W2 + N*b2 ; c = b1.s2   — one block per (b,modality)
__global__ void gate_s2(const float* __restrict__ pA, const float* __restrict__ pD,
                        const float* __restrict__ w2a, const float* __restrict__ b2a,
                        const float* __restrict__ w2d, const float* __restrict__ b2d,
                        const float* __restrict__ b1a, const float* __restrict__ b1d,
                        float* __restrict__ s2, float* __restrict__ cAB){
  __shared__ float sums[D]; __shared__ float red[4];
  int blk = blockIdx.x; int b = blk>>1; int mod = blk&1;
  int t = threadIdx.x;
  const float* pX = mod? pD : pA;
  const float* w2 = mod? w2d : w2a;
  const float* b2 = mod? b2d : b2a;
  const float* b1 = mod? b1d : b1a;
  float s=0.f;
  for(int c=0;c<CCHK;++c) s += pX[((size_t)b*CCHK+c)*D+t];
  sums[t]=s; __syncthreads();
  float v=0.f;
  for(int i=0;i<D;++i) v += sums[i]*w2[(size_t)i*D+t];
  v += (float)NSRC * b2[t];
  s2[(size_t)blk*D + t] = v;
  float c = bred_sum(b1[t]*v, red);
  if(t==0) cAB[mod*BSZ + b] = c;
}

// t = W1 @ s2 — one wave per output element (2048 waves)
__global__ void gate_t(const float* __restrict__ w1a, const float* __restrict__ w1d,
                       const float* __restrict__ s2,
                       float* __restrict__ tA, float* __restrict__ tD){
  int gw = blockIdx.x*4 + (threadIdx.x>>6);
  int lane = threadIdx.x & 63;
  int i = gw & 255; int bm = gw >> 8;      // bm = b*2+mod
  int mod = bm & 1, b = bm >> 1;
  const float* w1 = mod? w1d : w1a;
  const float* s2v = s2 + (size_t)bm*D;
  float4 wv = *(const float4*)(w1 + (size_t)i*D + lane*4);
  float4 sv = *(const float4*)(s2v + lane*4);
  float d = wv.x*sv.x + wv.y*sv.y + wv.z*sv.z + wv.w*sv.w;
  d = wred_sum(d);
  if(lane==0){
    if(mod) tD[b*D+i] = d; else tA[b*D+i] = d;
  }
}

// per-row gate softmax + fused src (emits bf16)
__global__ void gate_src(const float* __restrict__ aps, const float* __restrict__ dvs,
                         const float* __restrict__ tA, const float* __restrict__ tD,
                         const float* __restrict__ cAB, unsigned short* __restrict__ srcb){
  int w = threadIdx.x >> 6, lane = threadIdx.x & 63;
  size_t row = (size_t)blockIdx.x*4 + w;
  int b = (int)(row / NSRC);
  const float4* ap = (const float4*)(aps + row*D);
  const float4* dp = (const float4*)(dvs + row*D);
  const float4* tap = (const float4*)(tA + (size_t)b*D);
  const float4* tdp = (const float4*)(tD + (size_t)b*D);
  float4 a = ap[lane], dd = dp[lane], ta = tap[lane], td = tdp[lane];
  float ga = a.x*ta.x + a.y*ta.y + a.z*ta.z + a.w*ta.w;
  float gd = dd.x*td.x + dd.y*td.y + dd.z*td.z + dd.w*td.w;
  ga = (wred_sum(ga) + cAB[b]) * 0.0625f;       // 1/sqrt(256)
  gd = (wred_sum(gd) + cAB[BSZ+b]) * 0.0625f;
  float m = fmaxf(ga,gd);
  float ea = expf(ga-m), ed = expf(gd-m);
  float inv = 1.f/(ea+ed);
  float wa = ea*inv, wd = ed*inv;
  ushort4 o;
  o.x = f2bf(wa*a.x + wd*dd.x); o.y = f2bf(wa*a.y + wd*dd.y);
  o.z = f2bf(wa*a.z + wd*dd.z); o.w = f2bf(wa*a.w + wd*dd.w);
  ((ushort4*)(srcb + row*D))[lane] = o;
}

// all weight transpose+convert in one launch: Bt[l][n][k] = bf16(W[l][k][n])
__global__ void wconv_all(const float* __restrict__ valw, const float* __restrict__ saqkvw,
                          const float* __restrict__ saoutw, const float* __restrict__ coutw,
                          const float* __restrict__ ffw1, const float* __restrict__ ffw2,
                          unsigned short* __restrict__ valT, unsigned short* __restrict__ qkvT,
                          unsigned short* __restrict__ saoutT, unsigned short* __restrict__ coutT,
                          unsigned short* __restrict__ ff1T, unsigned short* __restrict__ ff2T){
  __shared__ float tile[32][33];
  int bid = blockIdx.x;
  const float* W; unsigned short* Bt; int K, N, rel;
  if(bid < 384)      { W=valw;   Bt=valT;   K=256;  N=256;  rel=bid; }
  else if(bid < 1536){ W=saqkvw; Bt=qkvT;   K=256;  N=768;  rel=bid-384; }
  else if(bid < 1920){ W=saoutw; Bt=saoutT; K=256;  N=256;  rel=bid-1536; }
  else if(bid < 2304){ W=coutw;  Bt=coutT;  K=256;  N=256;  rel=bid-1920; }
  else if(bid < 3840){ W=ffw1;   Bt=ff1T;   K=256;  N=1024; rel=bid-2304; }
  else               { W=ffw2;   Bt=ff2T;   K=1024; N=256;  rel=bid-3840; }
  int nk = K>>5, nn = N>>5, tpl = nk*nn;
  int l = rel/tpl, rem = rel%tpl;
  int tk = rem % nk, tn = rem / nk;
  int tx = threadIdx.x & 31, ty = threadIdx.x >> 5;
  const float* Wl = W + (size_t)l*K*N;
  unsigned short* Btl = Bt + (size_t)l*N*K;
#pragma unroll
  for(int i=0;i<4;++i)
    tile[ty+i*8][tx] = Wl[(size_t)(tk*32+ty+i*8)*N + tn*32+tx];
  __syncthreads();
#pragma unroll
  for(int i=0;i<4;++i)
    Btl[(size_t)(tn*32+ty+i*8)*K + tk*32+tx] = f2bf(tile[tx][ty+i*8]);
}

__global__ void init_out_ref(const float* __restrict__ qe, const float* __restrict__ refw,
                             const float* __restrict__ refb,
                             float* __restrict__ outb, unsigned short* __restrict__ out_bf,
                             unsigned short* __restrict__ outpos_bf,
                             float* __restrict__ refp, float* __restrict__ dout){
  __shared__ float red[4];
  int q = blockIdx.x, t = threadIdx.x;
  float pos = qe[(size_t)q*2*D + t];
  float tgt = qe[(size_t)q*2*D + D + t];
  unsigned short tb = f2bf(tgt), tpb = f2bf(tgt+pos);
  for(int b=0;b<BSZ;++b){
    outb[((size_t)b*NQ+q)*D + t] = tgt;
    out_bf[((size_t)b*NQ+q)*D + t] = tb;
    outpos_bf[((size_t)b*NQ+q)*D + t] = tpb;
  }
  float d0 = bred_sum(pos*refw[t*2+0], red);
  float d1 = bred_sum(pos*refw[t*2+1], red);
  if(t<2){
    float dot = (t==0? d0 : d1) + refb[t];
    float r = 1.f/(1.f+expf(-dot));
    refp[q*2+t] = r;
    const size_t o1 = (size_t)BSZ*NQ*D;
    const size_t o2 = o1 + (size_t)BSZ*NQ*2;
    for(int b=0;b<BSZ;++b){
      dout[o1 + (b*NQ+q)*2 + t] = r;
      dout[o2 + (b*NQ+q)*2 + t] = r;
    }
  }
}

// ---- unified bf16 MFMA GEMM (M-chain), 64x64 tile, FULL-K (BK=256) staging --
__global__ __launch_bounds__(256) void gemmb(
    const unsigned short* __restrict__ A,   // [M][K] bf16
    const unsigned short* __restrict__ A2,
    int ncut,
    const unsigned short* __restrict__ Bt,  // [N][K] bf16
    const float* __restrict__ bias,
    float* __restrict__ Cf, unsigned short* __restrict__ Cb,
    int M, int K, int N, int relu){
  __shared__ unsigned short As[64][256];
  __shared__ unsigned short Bs[64][256];
  int n0 = blockIdx.x*64, m0 = blockIdx.y*64;
  const unsigned short* Asrc = (A2 && n0 >= ncut) ? A2 : A;
  int t = threadIdx.x, wave = t>>6, lane = t&63;
  int wm = (wave>>1)*32, wn = (wave&1)*32;
  int hi = lane>>4, lo = lane&15;
  int lrow2 = lane>>5, lslot = lane&31;
  f32x4 acc[2][2];
#pragma unroll
  for(int i=0;i<2;++i)
#pragma unroll
    for(int j=0;j<2;++j)
#pragma unroll
      for(int r=0;r<4;++r) acc[i][j][r]=0.f;

  for(int k0=0;k0<K;k0+=256){
#pragma unroll
    for(int i=0;i<8;++i){
      int rt = wave*16 + 2*i + lrow2;          // tile row this lane feeds
      int col = ((lslot ^ (rt&7)))*8;          // pre-swizzled source slot
      int ga = m0+rt; if(ga >= M) ga = M-1;
      GLOAD_LDS(Asrc + (size_t)ga*K + k0 + col, &As[wave*16 + 2*i][0]);
      GLOAD_LDS(Bt + (size_t)(n0+rt)*K + k0 + col, &Bs[wave*16 + 2*i][0]);
    }
    __syncthreads();
#pragma unroll
    for(int kk=0;kk<8;++kk){
      int ps = (((kk*4+hi) ^ (lo&7)))*8;       // physical slot (elements)
      short8v a0 = *(short8v*)&As[wm+lo][ps];
      short8v a1 = *(short8v*)&As[wm+16+lo][ps];
      short8v b0 = *(short8v*)&Bs[wn+lo][ps];
      short8v b1 = *(short8v*)&Bs[wn+16+lo][ps];
      acc[0][0] = __builtin_amdgcn_mfma_f32_16x16x32_bf16(a0,b0,acc[0][0],0,0,0);
      acc[0][1] = __builtin_amdgcn_mfma_f32_16x16x32_bf16(a0,b1,acc[0][1],0,0,0);
      acc[1][0] = __builtin_amdgcn_mfma_f32_16x16x32_bf16(a1,b0,acc[1][0],0,0,0);
      acc[1][1] = __builtin_amdgcn_mfma_f32_16x16x32_bf16(a1,b1,acc[1][1],0,0,0);
    }
    if(k0 + 256 < K) __syncthreads();
  }
#pragma unroll
  for(int mf=0;mf<2;++mf){
#pragma unroll
    for(int nf=0;nf<2;++nf){
      int col = n0 + wn + nf*16 + lo;
      float bv = bias[col];
#pragma unroll
      for(int r=0;r<4;++r){
        int row = m0 + wm + mf*16 + hi*4 + r;
        if(row < M){
          float v = acc[mf][nf][r] + bv;
          if(relu) v = fmaxf(v, 0.f);
          if(Cf) Cf[(size_t)row*N+col] = v;
          if(Cb) Cb[(size_t)row*N+col] = f2bf(v);
        }
      }
    }
  }
}

// ------- bf16 MFMA value GEMM for ALL layers: [36864,256]@[256,1536] --------
// double-buffered LDS + global_load_lds + XCD swizzle + slot XOR bank swizzle
__global__ __launch_bounds__(256) void mfma_value6(
    const unsigned short* __restrict__ Abf,   // [M][256] bf16
    const unsigned short* __restrict__ Bt,    // [1536][256] bf16 (all layers)
    const float* __restrict__ bias,           // [1536] (valb flat)
    const unsigned char* __restrict__ rowmask,
    unsigned short* __restrict__ C){          // [M][1536] bf16
  __shared__ unsigned short As[2][128][32];
  __shared__ unsigned short Bs[2][128][32];
  // bijective XCD swizzle: 3456 blocks = 8 x 432; each XCD gets 36 m-panels x 12 n
  int id = blockIdx.x;
  int swz = (id & 7)*432 + (id >> 3);
  int m0 = (swz/12)*128, n0 = (swz%12)*128;
  int t = threadIdx.x;
  int wave = t>>6, lane = t&63;
  int wm = (wave>>1)*64, wn = (wave&1)*64;
  f32x4 acc[4][4];
#pragma unroll
  for(int i=0;i<4;++i)
#pragma unroll
    for(int j=0;j<4;++j)
#pragma unroll
      for(int r=0;r<4;++r) acc[i][j][r]=0.f;

  // staging with pre-swizzled global column: phys slot (l&3) holds logical
  // slot (l&3)^((row>>1)&3); row = wave*32 + (l>>2)  (and +16 variant)
  int colx = ((lane&3) ^ ((lane>>3)&3)) * 8;
  const unsigned short* Ag = Abf + (size_t)(m0 + wave*32 + (lane>>2))*256 + colx;
  const unsigned short* Bg = Bt  + (size_t)(n0 + wave*32 + (lane>>2))*256 + colx;

  int hi = lane>>4, lo = lane&15;
  int sx = (hi ^ ((lo>>1)&3)) * 8;   // read-side physical slot (elements)

  // prologue: stage k=0 into buffer 0
  GLOAD_LDS(Ag,          &As[0][wave*32][0]);
  GLOAD_LDS(Ag + 16*256, &As[0][wave*32+16][0]);
  GLOAD_LDS(Bg,          &Bs[0][wave*32][0]);
  GLOAD_LDS(Bg + 16*256, &Bs[0][wave*32+16][0]);
  __syncthreads();

  for(int k=0;k<8;++k){
    int cur = k & 1;
    if(k < 7){
      int k1 = (k+1)*32;
      GLOAD_LDS(Ag + k1,          &As[cur^1][wave*32][0]);
      GLOAD_LDS(Ag + k1 + 16*256, &As[cur^1][wave*32+16][0]);
      GLOAD_LDS(Bg + k1,          &Bs[cur^1][wave*32][0]);
      GLOAD_LDS(Bg + k1 + 16*256, &Bs[cur^1][wave*32+16][0]);
    }
    short8v a[4], bb[4];
#pragma unroll
    for(int mf=0;mf<4;++mf) a[mf]  = *(short8v*)&As[cur][wm+mf*16+lo][sx];
#pragma unroll
    for(int nf=0;nf<4;++nf) bb[nf] = *(short8v*)&Bs[cur][wn+nf*16+lo][sx];
#pragma unroll
    for(int mf=0;mf<4;++mf)
#pragma unroll
      for(int nf=0;nf<4;++nf)
        acc[mf][nf] = __builtin_amdgcn_mfma_f32_16x16x32_bf16(a[mf], bb[nf], acc[mf][nf], 0,0,0);
    __syncthreads();
  }
#pragma unroll
  for(int mf=0;mf<4;++mf){
    int rbase = m0 + wm + mf*16 + (lane>>4)*4;
#pragma unroll
    for(int nf=0;nf<4;++nf){
      int col = n0 + wn + nf*16 + (lane&15);
      float bv = bias[col];
#pragma unroll
      for(int r=0;r<4;++r){
        int row = rbase + r;
        float v = acc[mf][nf][r] + bv;
        if(rowmask[row]) v = 0.f;
        C[(size_t)row*VSTRIDE + col] = f2bf(v);
      }
    }
  }
}

// ---------------- MFMA self attention: block = (b,h) x 64-row Q tile --------
__global__ __launch_bounds__(256) void self_attn_mfma(
    const unsigned short* __restrict__ qkvh, // [1200][768] bf16 (q|k|v)
    unsigned short* __restrict__ sa){        // [1200][256] bf16
  __shared__ unsigned short P[64][328];
  __shared__ unsigned short Vt[32][328];
  int blk = blockIdx.x;
  int qt = blk % 5; int bh = blk / 5; int h = bh % NHD; int b = bh / NHD;
  int t = threadIdx.x, wv = t>>6, lane = t&63;
  int hi = lane>>4, lo = lane&15;
  {
    int c = t & 31, rb = t >> 5;
    for(int r = rb; r < 320; r += 8){
      unsigned short v = 0;
      if(r < 300) v = qkvh[(size_t)(b*300+r)*768 + 512 + h*32 + c];
      Vt[c][r] = v;
    }
  }
  __syncthreads();
  int m0 = qt*64 + wv*16;
  int qr = m0 + lo; if(qr > 299) qr = 299;
  short8v aq = *(const short8v*)(qkvh + (size_t)(b*300+qr)*768 + h*32 + hi*8);
  f32x4 s[19];
#pragma unroll
  for(int nt=0; nt<19; ++nt){
    int kr = nt*16 + lo; if(kr > 299) kr = 299;
    short8v bk = *(const short8v*)(qkvh + (size_t)(b*300+kr)*768 + 256 + h*32 + hi*8);
    f32x4 z; z[0]=0.f; z[1]=0.f; z[2]=0.f; z[3]=0.f;
    s[nt] = __builtin_amdgcn_mfma_f32_16x16x32_bf16(aq, bk, z, 0,0,0);
  }
  const float kSc = 0.25506009837f;   // (1/sqrt(32)) * log2(e)
  float inv[4];
#pragma unroll
  for(int ri=0; ri<4; ++ri){
    float m = -1e30f;
#pragma unroll
    for(int nt=0; nt<19; ++nt){
      if(nt*16+lo < 300) m = fmaxf(m, s[nt][ri]);
    }
#pragma unroll
    for(int o=8;o>=1;o>>=1) m = fmaxf(m, __shfl_xor(m,o,64));
    float sum = 0.f;
#pragma unroll
    for(int nt=0; nt<19; ++nt){
      float p = 0.f;
      if(nt*16+lo < 300) p = exp2f((s[nt][ri]-m)*kSc);
      sum += p;
      P[wv*16 + hi*4 + ri][nt*16 + lo] = f2bf(p);
    }
    P[wv*16 + hi*4 + ri][304 + lo] = 0;
#pragma unroll
    for(int o=8;o>=1;o>>=1) sum += __shfl_xor(sum,o,64);
    inv[ri] = 1.f/sum;
  }
  f32x4 o0, o1;
#pragma unroll
  for(int r=0;r<4;++r){ o0[r]=0.f; o1[r]=0.f; }
#pragma unroll
  for(int kt=0; kt<10; ++kt){
    short8v ap = *(short8v*)&P[wv*16 + lo][kt*32 + hi*8];
    short8v b0 = *(short8v*)&Vt[lo][kt*32 + hi*8];
    short8v b1 = *(short8v*)&Vt[16+lo][kt*32 + hi*8];
    o0 = __builtin_amdgcn_mfma_f32_16x16x32_bf16(ap, b0, o0, 0,0,0);
    o1 = __builtin_amdgcn_mfma_f32_16x16x32_bf16(ap, b1, o1, 0,0,0);
  }
#pragma unroll
  for(int ri=0; ri<4; ++ri){
    int r = m0 + hi*4 + ri;
    if(r < 300){
      size_t base = (size_t)(b*300+r)*256 + h*32;
      sa[base + lo]      = f2bf(o0[ri]*inv[ri]);
      sa[base + 16 + lo] = f2bf(o1[ri]*inv[ri]);
    }
  }
}

// ------- residual + layernorm, one ROW per WAVE, float4 loads, no LDS -------
__global__ void residual_ln(const float* __restrict__ base, const float* __restrict__ delta,
                            const float* __restrict__ lw, const float* __restrict__ lb,
                            float* __restrict__ dstf, unsigned short* __restrict__ dstb,
                            unsigned short* __restrict__ dstp, const float* __restrict__ qe){
  int w = threadIdx.x >> 6, lane = threadIdx.x & 63;
  size_t row = (size_t)blockIdx.x*4 + w;
  float4 bv = ((const float4*)(base + row*D))[lane];
  float4 dv = ((const float4*)(delta + row*D))[lane];
  float4 v; v.x=bv.x+dv.x; v.y=bv.y+dv.y; v.z=bv.z+dv.z; v.w=bv.w+dv.w;
  float s = wred_sum(v.x+v.y+v.z+v.w);
  float mean = s * (1.f/D);
  float4 c; c.x=v.x-mean; c.y=v.y-mean; c.z=v.z-mean; c.w=v.w-mean;
  float vs = wred_sum(c.x*c.x + c.y*c.y + c.z*c.z + c.w*c.w);
  float inv = rsqrtf(vs*(1.f/D) + LNEPS);
  float4 wv = ((const float4*)lw)[lane];
  float4 lbv = ((const float4*)lb)[lane];
  float4 y; y.x=c.x*inv*wv.x+lbv.x; y.y=c.y*inv*wv.y+lbv.y;
  y.z=c.z*inv*wv.z+lbv.z; y.w=c.w*inv*wv.w+lbv.w;
  ((float4*)(dstf + row*D))[lane] = y;
  if(dstb){
    ushort4 o; o.x=f2bf(y.x); o.y=f2bf(y.y); o.z=f2bf(y.z); o.w=f2bf(y.w);
    ((ushort4*)(dstb + row*D))[lane] = o;
  }
  if(dstp){
    int q = (int)(row % NQ);
    float4 qv = ((const float4*)(qe + (size_t)q*2*D))[lane];
    ushort4 o; o.x=f2bf(y.x+qv.x); o.y=f2bf(y.y+qv.y);
    o.z=f2bf(y.z+qv.z); o.w=f2bf(y.w+qv.w);
    ((ushort4*)(dstp + row*D))[lane] = o;
  }
}

// ---- fused: residual+LN (post-saout) + deformable cross-attn ---------------
__global__ void deform_attn_ln(const float* __restrict__ base, const float* __restrict__ delta,
                               const float* __restrict__ lnw, const float* __restrict__ lnb,
                               float* __restrict__ outb,      // LN result written back
                               const float* __restrict__ qe,
                               const float* __restrict__ offw, const float* __restrict__ offb,
                               const float* __restrict__ attnw, const float* __restrict__ attnb,
                               const unsigned short* __restrict__ value, const float* __restrict__ refp,
                               const float* __restrict__ vr, const int* __restrict__ sshape,
                               unsigned short* __restrict__ ca){
  __shared__ float qrow[D];
  __shared__ float part[96][2];
  __shared__ float proj[96];
  __shared__ float red[4];
  int row = blockIdx.x; int b = row / NQ; int q = row % NQ;
  int t = threadIdx.x;
  // residual + LN (per-row, full row in block)
  float v = base[(size_t)row*D+t] + delta[(size_t)row*D+t];
  float mean = bred_sum(v, red) * (1.f/D);
  float c = v - mean;
  float var = bred_sum(c*c, red) * (1.f/D);
  float y = c * rsqrtf(var + LNEPS) * lnw[t] + lnb[t];
  outb[(size_t)row*D+t] = y;
  qrow[t] = y + qe[(size_t)q*2*D + t];
  __syncthreads();
  if(t < 192){
    int col = t >> 1, half = t & 1;
    float acc = 0.f;
    if(col < 64){
      const float* W = offw;
      for(int k=half*128; k<half*128+128; ++k) acc += qrow[k]*W[(size_t)k*64 + col];
    } else {
      const float* W = attnw; int cc = col-64;
      for(int k=half*128; k<half*128+128; ++k) acc += qrow[k]*W[(size_t)k*32 + cc];
    }
    part[col][half] = acc;
  }
  __syncthreads();
  if(t < 96) proj[t] = part[t][0] + part[t][1] + (t<64 ? offb[t] : attnb[t-64]);
  __syncthreads();

  int h = t>>5, hd = t&31;
  float Hf = (float)sshape[0], Wf = (float)sshape[1];
  int Ws = sshape[1];
  float rx = refp[q*2+0] * vr[b*2+0];
  float ry = refp[q*2+1] * vr[b*2+1];
  const float* lg = &proj[64 + h*4];
  float m = fmaxf(fmaxf(lg[0],lg[1]),fmaxf(lg[2],lg[3]));
  float e[4]; float esum=0.f;
#pragma unroll
  for(int p=0;p<4;++p){ e[p]=expf(lg[p]-m); esum+=e[p]; }
  float einv = 1.f/esum;
  const float* ofr = &proj[h*8];
  const unsigned short* vbase = value + ((size_t)b*NSRC)*VSTRIDE + h*HDIM + hd;
  float acc = 0.f;
#pragma unroll
  for(int p=0;p<NPTS;++p){
    float lx = rx + ofr[p*2+0]/Wf;
    float ly = ry + ofr[p*2+1]/Hf;
    float x = lx*Wf - 0.5f, y2 = ly*Hf - 0.5f;
    float x0 = floorf(x), y0 = floorf(y2);
    float wx = x-x0, wy = y2-y0;
    float sample = 0.f;
#pragma unroll
    for(int cy=0;cy<2;++cy){
#pragma unroll
      for(int cx=0;cx<2;++cx){
        float xi = x0+cx, yi = y0+cy;
        float wgt = (cx? wx : 1.f-wx) * (cy? wy : 1.f-wy);
        bool valid = (xi>=0.f)&&(xi<=Wf-1.f)&&(yi>=0.f)&&(yi<=Hf-1.f);
        if(valid){
          int idx = (int)fminf(fmaxf(yi,0.f),Hf-1.f)*Ws + (int)fminf(fmaxf(xi,0.f),Wf-1.f);
          sample += wgt * bf2f(vbase[(size_t)idx*VSTRIDE]);
        }
      }
    }
    acc += (e[p]*einv) * sample;
  }
  ca[(size_t)row*D + h*HDIM + hd] = f2bf(acc);
}

// ---------------- host ----------------
extern "C" void kernel_launch(void* const* d_in, const int* in_sizes, int n_in,
                              void* d_out, int out_size, void* d_ws, size_t ws_size,
                              hipStream_t stream){
  const float* aps=(const float*)d_in[0];
  const float* dvs=(const float*)d_in[1];
  const float* qe =(const float*)d_in[2];
  const float* vr =(const float*)d_in[3];
  const float* aps_w1=(const float*)d_in[4]; const float* aps_b1=(const float*)d_in[5];
  const float* aps_w2=(const float*)d_in[6]; const float* aps_b2=(const float*)d_in[7];
  const float* dvs_w1=(const float*)d_in[8]; const float* dvs_b1=(const float*)d_in[9];
  const float* dvs_w2=(const float*)d_in[10]; const float* dvs_b2=(const float*)d_in[11];
  const float* ref_w=(const float*)d_in[12]; const float* ref_b=(const float*)d_in[13];
  const float* saqkvw=(const float*)d_in[14]; const float* saqkvb=(const float*)d_in[15];
  const float* saoutw=(const float*)d_in[16]; const float* saoutb=(const float*)d_in[17];
  const float* offw=(const float*)d_in[18]; const float* offb=(const float*)d_in[19];
  const float* attnw=(const float*)d_in[20]; const float* attnb=(const float*)d_in[21];
  const float* valw=(const float*)d_in[22]; const float* valb=(const float*)d_in[23];
  const float* coutw=(const float*)d_in[24]; const float* coutb=(const float*)d_in[25];
  const float* ln1w=(const float*)d_in[26]; const float* ln1b=(const float*)d_in[27];
  const float* ln2w=(const float*)d_in[28]; const float* ln2b=(const float*)d_in[29];
  const float* ln3w=(const float*)d_in[30]; const float* ln3b=(const float*)d_in[31];
  const float* ffw1=(const float*)d_in[32]; const float* ffb1=(const float*)d_in[33];
  const float* ffw2=(const float*)d_in[34]; const float* ffb2=(const float*)d_in[35];
  const unsigned char* mask=(const unsigned char*)d_in[36];
  const int* sshape=(const int*)d_in[37];
  float* out = (float*)d_out;

  char* wsb = (char*)d_ws;
  size_t o = 0;
  unsigned short* srcb   = (unsigned short*)(wsb+o); o += (size_t)NVROWS*D*2;
  unsigned short* valT   = (unsigned short*)(wsb+o); o += (size_t)NLAY*D*D*2;
  unsigned short* qkvT   = (unsigned short*)(wsb+o); o += (size_t)NLAY*3*D*D*2;
  unsigned short* saoutT = (unsigned short*)(wsb+o); o += (size_t)NLAY*D*D*2;
  unsigned short* coutT  = (unsigned short*)(wsb+o); o += (size_t)NLAY*D*D*2;
  unsigned short* ff1T   = (unsigned short*)(wsb+o); o += (size_t)NLAY*D*FFD*2;
  unsigned short* ff2T   = (unsigned short*)(wsb+o); o += (size_t)NLAY*FFD*D*2;
  unsigned short* value  = (unsigned short*)(wsb+o); o += (size_t)NVROWS*VSTRIDE*2;
  float* pA    = (float*)(wsb+o); o += (size_t)BSZ*CCHK*D*4;
  float* pD    = (float*)(wsb+o); o += (size_t)BSZ*CCHK*D*4;
  float* s2    = (float*)(wsb+o); o += 2*BSZ*D*4;
  float* tA    = (float*)(wsb+o); o += BSZ*D*4;
  float* tD    = (float*)(wsb+o); o += BSZ*D*4;
  float* cAB   = (float*)(wsb+o); o += 16*4;
  float* refp  = (float*)(wsb+o); o += NQ*2*4;
  float* outb  = (float*)(wsb+o); o += (size_t)NROWS*D*4;
  float* tmpb  = (float*)(wsb+o); o += (size_t)NROWS*D*4;
  unsigned short* out_bf    = (unsigned short*)(wsb+o); o += (size_t)NROWS*D*2;
  unsigned short* outpos_bf = (unsigned short*)(wsb+o); o += (size_t)NROWS*D*2;
  unsigned short* qkvh_bf   = (unsigned short*)(wsb+o); o += (size_t)NROWS*3*D*2;
  unsigned short* sa_bf     = (unsigned short*)(wsb+o); o += (size_t)NROWS*D*2;
  unsigned short* ca_bf     = (unsigned short*)(wsb+o); o += (size_t)NROWS*D*2;
  unsigned short* ffh_bf    = (unsigned short*)(wsb+o); o += (size_t)NROWS*FFD*2;

  // ---- prologue
  colsum_partial<<<BSZ*CCHK,256,0,stream>>>(aps,dvs,pA,pD);
  gate_s2<<<2*BSZ,256,0,stream>>>(pA,pD,aps_w2,aps_b2,dvs_w2,dvs_b2,aps_b1,dvs_b1,s2,cAB);
  gate_t<<<512,256,0,stream>>>(aps_w1,dvs_w1,s2,tA,tD);
  gate_src<<<NVROWS/4,256,0,stream>>>(aps,dvs,tA,tD,cAB,srcb);
  wconv_all<<<5376,256,0,stream>>>(valw,saqkvw,saoutw,coutw,ffw1,ffw2,
                                   valT,qkvT,saoutT,coutT,ff1T,ff2T);
  init_out_ref<<<NQ,256,0,stream>>>(qe,ref_w,ref_b,outb,out_bf,outpos_bf,refp,out);
  mfma_value6<<<(NVROWS/128)*(VSTRIDE/128),256,0,stream>>>(srcb, valT, valb, mask, value);

  dim3 gqkv(12,19), g256(4,19), gffu(16,19);

  for(int l=0;l<NLAY;++l){
    const unsigned short* qkvTl = qkvT + (size_t)l*3*D*D;
    const float* bqkv = saqkvb + (size_t)l*3*D;
    // self attention: q,k from out+qpos, v from out — one fused GEMM (N=768)
    gemmb<<<gqkv,256,0,stream>>>(outpos_bf, out_bf, 512, qkvTl, bqkv,
                                 nullptr, qkvh_bf, NROWS, D, 3*D, 0);
    self_attn_mfma<<<BSZ*NHD*5,256,0,stream>>>(qkvh_bf, sa_bf);
    gemmb<<<g256,256,0,stream>>>(sa_bf, nullptr, 0, saoutT+(size_t)l*D*D, saoutb+(size_t)l*D,
                                 tmpb, nullptr, NROWS, D, D, 0);

    // fused: residual+LN(ln2) + deformable cross attention
    deform_attn_ln<<<NROWS,256,0,stream>>>(outb, tmpb, ln2w+(size_t)l*D, ln2b+(size_t)l*D,
                                           outb, qe,
                                           offw+(size_t)l*D*64, offb+(size_t)l*64,
                                           attnw+(size_t)l*D*32, attnb+(size_t)l*32,
                                           value + (size_t)l*D, refp, vr, sshape, ca_bf);
    gemmb<<<g256,256,0,stream>>>(ca_bf, nullptr, 0, coutT+(size_t)l*D*D, coutb+(size_t)l*D,
                                 tmpb, nullptr, NROWS, D, D, 0);
    residual_ln<<<NROWS/4,256,0,stream>>>(outb,tmpb,ln1w+(size_t)l*D,ln1b+(size_t)l*D,
                                          outb,out_bf,nullptr,qe);

    // FFN
    gemmb<<<gffu,256,0,stream>>>(out_bf, nullptr, 0, ff1T+(size_t)l*D*FFD, ffb1+(size_t)l*FFD,
                                 nullptr, ffh_bf, NROWS, D, FFD, 1);
    gemmb<<<g256,256,0,stream>>>(ffh_bf, nullptr, 0, ff2T+(size_t)l*FFD*D, ffb2+(size_t)l*D,
                                 tmpb, nullptr, NROWS, FFD, D, 0);
    if(l==NLAY-1)
      residual_ln<<<NROWS/4,256,0,stream>>>(outb,tmpb,ln3w+(size_t)l*D,ln3b+(size_t)l*D,
                                            out,nullptr,nullptr,qe);
    else
      residual_ln<<<NROWS/4,256,0,stream>>>(outb,tmpb,ln3w+(size_t)l*D,ln3b+(size_t)l*D,
                                            outb,out_bf,outpos_bf,qe);
  }
}

// Round 14
// 614.449 us; speedup vs baseline: 1.0119x; 1.0033x over previous
//
#include <hip/hip_runtime.h>
#include <math.h>

#define D 256
#define NHD 8
#define HDIM 32
#define NPTS 4
#define NLAY 6
#define FFD 1024
#define BSZ 4
#define NSRC 9216
#define NQ 300
#define NROWS (BSZ*NQ)      // 1200
#define NVROWS (BSZ*NSRC)   // 36864
#define CCHK 256            // colsum chunks per batch (36 rows each)
#define VSTRIDE 1536        // value6 row stride (6 layers x 256)
#define LNEPS 1e-5f

typedef __attribute__((ext_vector_type(8))) short short8v;
typedef __attribute__((ext_vector_type(4))) float f32x4;

// async global->LDS, 16B per lane; dest = wave-uniform base + lane*16
#define GLOAD_LDS(g, l) __builtin_amdgcn_global_load_lds( \
    (const __attribute__((address_space(1))) void*)(g), \
    (__attribute__((address_space(3))) void*)(l), 16, 0, 0)

__device__ __forceinline__ unsigned short f2bf(float f){
  unsigned u = __float_as_uint(f);
  unsigned r = (u + 0x7FFFu + ((u>>16)&1u)) >> 16;
  return (unsigned short)r;
}
__device__ __forceinline__ float bf2f(unsigned short u){
  return __uint_as_float(((unsigned)u)<<16);
}

// ---------------- reduction helpers ----------------
__device__ __forceinline__ float wred_sum(float v){
#pragma unroll
  for(int o=32;o>=1;o>>=1) v += __shfl_xor(v,o,64);
  return v;
}
__device__ __forceinline__ float bred_sum(float v, float* s){
  v = wred_sum(v);
  int lane = threadIdx.x & 63, wid = threadIdx.x >> 6;
  if(lane==0) s[wid]=v;
  __syncthreads();
  float r = s[0]+s[1]+s[2]+s[3];
  __syncthreads();
  return r;
}

// ---------------- gating front-end ----------------
__global__ void colsum_partial(const float* __restrict__ aps, const float* __restrict__ dvs,
                               float* __restrict__ pA, float* __restrict__ pD){
  __shared__ float4 sA[4][64]; __shared__ float4 sD[4][64];
  int blk = blockIdx.x; int b = blk / CCHK; int c = blk % CCHK;
  int t = threadIdx.x; int cl = t & 63; int rg = t >> 6;
  const int rows = NSRC / CCHK;   // 36
  size_t base = ((size_t)b*NSRC + (size_t)c*rows)*D + cl*4;
  float4 sa = make_float4(0.f,0.f,0.f,0.f), sd = sa;
  for(int r=rg; r<rows; r+=4){
    float4 va = *(const float4*)(aps + base + (size_t)r*D);
    float4 vd = *(const float4*)(dvs + base + (size_t)r*D);
    sa.x+=va.x; sa.y+=va.y; sa.z+=va.z; sa.w+=va.w;
    sd.x+=vd.x; sd.y+=vd.y; sd.z+=vd.z; sd.w+=vd.w;
  }
  sA[rg][cl]=sa; sD[rg][cl]=sd;
  __syncthreads();
  if(t < 64){
    float4 r0=sA[0][t],r1=sA[1][t],r2=sA[2][t],r3=sA[3][t];
    float4 o; o.x=r0.x+r1.x+r2.x+r3.x; o.y=r0.y+r1.y+r2.y+r3.y;
    o.z=r0.z+r1.z+r2.z+r3.z; o.w=r0.w+r1.w+r2.w+r3.w;
    *(float4*)(pA + ((size_t)b*CCHK+c)*D + t*4) = o;
  } else if(t < 128){
    int u=t-64;
    float4 r0=sD[0][u],r1=sD[1][u],r2=sD[2][u],r3=sD[3][u];
    float4 o; o.x=r0.x+r1.x+r2.x+r3.x; o.y=r0.y+r1.y+r2.y+r3.y;
    o.z=r0.z+r1.z+r2.z+r3.z; o.w=r0.w+r1.w+r2.w+r3.w;
    *(float4*)(pD + ((size_t)b*CCHK+c)*D + u*4) = o;
  }
}

// s2 = colsum@W2 + N*b2 ; c = b1.s2   — one block per (b,modality)
__global__ void gate_s2(const float* __restrict__ pA, const float* __restrict__ pD,
                        const float* __restrict__ w2a, const float* __restrict__ b2a,
                        const float* __restrict__ w2d, const float* __restrict__ b2d,
                        const float* __restrict__ b1a, const float* __restrict__ b1d,
                        float* __restrict__ s2, float* __restrict__ cAB){
  __shared__ float sums[D]; __shared__ float red[4];
  int blk = blockIdx.x; int b = blk>>1; int mod = blk&1;
  int t = threadIdx.x;
  const float* pX = mod? pD : pA;
  const float* w2 = mod? w2d : w2a;
  const float* b2 = mod? b2d : b2a;
  const float* b1 = mod? b1d : b1a;
  float s=0.f;
  for(int c=0;c<CCHK;++c) s += pX[((size_t)b*CCHK+c)*D+t];
  sums[t]=s; __syncthreads();
  float v=0.f;
  for(int i=0;i<D;++i) v += sums[i]*w2[(size_t)i*D+t];
  v += (float)NSRC * b2[t];
  s2[(size_t)blk*D + t] = v;
  float c = bred_sum(b1[t]*v, red);
  if(t==0) cAB[mod*BSZ + b] = c;
}

// t = W1 @ s2 — one wave per output element (2048 waves)
__global__ void gate_t(const float* __restrict__ w1a, const float* __restrict__ w1d,
                       const float* __restrict__ s2,
                       float* __restrict__ tA, float* __restrict__ tD){
  int gw = blockIdx.x*4 + (threadIdx.x>>6);
  int lane = threadIdx.x & 63;
  int i = gw & 255; int bm = gw >> 8;      // bm = b*2+mod
  int mod = bm & 1, b = bm >> 1;
  const float* w1 = mod? w1d : w1a;
  const float* s2v = s2 + (size_t)bm*D;
  float4 wv = *(const float4*)(w1 + (size_t)i*D + lane*4);
  float4 sv = *(const float4*)(s2v + lane*4);
  float d = wv.x*sv.x + wv.y*sv.y + wv.z*sv.z + wv.w*sv.w;
  d = wred_sum(d);
  if(lane==0){
    if(mod) tD[b*D+i] = d; else tA[b*D+i] = d;
  }
}

// per-row gate softmax + fused src (emits bf16)
__global__ void gate_src(const float* __restrict__ aps, const float* __restrict__ dvs,
                         const float* __restrict__ tA, const float* __restrict__ tD,
                         const float* __restrict__ cAB, unsigned short* __restrict__ srcb){
  int w = threadIdx.x >> 6, lane = threadIdx.x & 63;
  size_t row = (size_t)blockIdx.x*4 + w;
  int b = (int)(row / NSRC);
  const float4* ap = (const float4*)(aps + row*D);
  const float4* dp = (const float4*)(dvs + row*D);
  const float4* tap = (const float4*)(tA + (size_t)b*D);
  const float4* tdp = (const float4*)(tD + (size_t)b*D);
  float4 a = ap[lane], dd = dp[lane], ta = tap[lane], td = tdp[lane];
  float ga = a.x*ta.x + a.y*ta.y + a.z*ta.z + a.w*ta.w;
  float gd = dd.x*td.x + dd.y*td.y + dd.z*td.z + dd.w*td.w;
  ga = (wred_sum(ga) + cAB[b]) * 0.0625f;       // 1/sqrt(256)
  gd = (wred_sum(gd) + cAB[BSZ+b]) * 0.0625f;
  float m = fmaxf(ga,gd);
  float ea = expf(ga-m), ed = expf(gd-m);
  float inv = 1.f/(ea+ed);
  float wa = ea*inv, wd = ed*inv;
  ushort4 o;
  o.x = f2bf(wa*a.x + wd*dd.x); o.y = f2bf(wa*a.y + wd*dd.y);
  o.z = f2bf(wa*a.z + wd*dd.z); o.w = f2bf(wa*a.w + wd*dd.w);
  ((ushort4*)(srcb + row*D))[lane] = o;
}

// all weight transpose+convert in one launch: Bt[l][n][k] = bf16(W[l][k][n])
__global__ void wconv_all(const float* __restrict__ valw, const float* __restrict__ saqkvw,
                          const float* __restrict__ saoutw, const float* __restrict__ coutw,
                          const float* __restrict__ ffw1, const float* __restrict__ ffw2,
                          unsigned short* __restrict__ valT, unsigned short* __restrict__ qkvT,
                          unsigned short* __restrict__ saoutT, unsigned short* __restrict__ coutT,
                          unsigned short* __restrict__ ff1T, unsigned short* __restrict__ ff2T){
  __shared__ float tile[32][33];
  int bid = blockIdx.x;
  const float* W; unsigned short* Bt; int K, N, rel;
  if(bid < 384)      { W=valw;   Bt=valT;   K=256;  N=256;  rel=bid; }
  else if(bid < 1536){ W=saqkvw; Bt=qkvT;   K=256;  N=768;  rel=bid-384; }
  else if(bid < 1920){ W=saoutw; Bt=saoutT; K=256;  N=256;  rel=bid-1536; }
  else if(bid < 2304){ W=coutw;  Bt=coutT;  K=256;  N=256;  rel=bid-1920; }
  else if(bid < 3840){ W=ffw1;   Bt=ff1T;   K=256;  N=1024; rel=bid-2304; }
  else               { W=ffw2;   Bt=ff2T;   K=1024; N=256;  rel=bid-3840; }
  int nk = K>>5, nn = N>>5, tpl = nk*nn;
  int l = rel/tpl, rem = rel%tpl;
  int tk = rem % nk, tn = rem / nk;
  int tx = threadIdx.x & 31, ty = threadIdx.x >> 5;
  const float* Wl = W + (size_t)l*K*N;
  unsigned short* Btl = Bt + (size_t)l*N*K;
#pragma unroll
  for(int i=0;i<4;++i)
    tile[ty+i*8][tx] = Wl[(size_t)(tk*32+ty+i*8)*N + tn*32+tx];
  __syncthreads();
#pragma unroll
  for(int i=0;i<4;++i)
    Btl[(size_t)(tn*32+ty+i*8)*K + tk*32+tx] = f2bf(tile[tx][ty+i*8]);
}

__global__ void init_out_ref(const float* __restrict__ qe, const float* __restrict__ refw,
                             const float* __restrict__ refb,
                             float* __restrict__ outb, unsigned short* __restrict__ out_bf,
                             unsigned short* __restrict__ outpos_bf,
                             float* __restrict__ refp, float* __restrict__ dout){
  __shared__ float red[4];
  int q = blockIdx.x, t = threadIdx.x;
  float pos = qe[(size_t)q*2*D + t];
  float tgt = qe[(size_t)q*2*D + D + t];
  unsigned short tb = f2bf(tgt), tpb = f2bf(tgt+pos);
  for(int b=0;b<BSZ;++b){
    outb[((size_t)b*NQ+q)*D + t] = tgt;
    out_bf[((size_t)b*NQ+q)*D + t] = tb;
    outpos_bf[((size_t)b*NQ+q)*D + t] = tpb;
  }
  float d0 = bred_sum(pos*refw[t*2+0], red);
  float d1 = bred_sum(pos*refw[t*2+1], red);
  if(t<2){
    float dot = (t==0? d0 : d1) + refb[t];
    float r = 1.f/(1.f+expf(-dot));
    refp[q*2+t] = r;
    const size_t o1 = (size_t)BSZ*NQ*D;
    const size_t o2 = o1 + (size_t)BSZ*NQ*2;
    for(int b=0;b<BSZ;++b){
      dout[o1 + (b*NQ+q)*2 + t] = r;
      dout[o2 + (b*NQ+q)*2 + t] = r;
    }
  }
}

// ---- unified bf16 MFMA GEMM (M-chain), 64x64 tile, FULL-K (BK=256) staging --
__global__ __launch_bounds__(256) void gemmb(
    const unsigned short* __restrict__ A,   // [M][K] bf16
    const unsigned short* __restrict__ A2,
    int ncut,
    const unsigned short* __restrict__ Bt,  // [N][K] bf16
    const float* __restrict__ bias,
    float* __restrict__ Cf, unsigned short* __restrict__ Cb,
    int M, int K, int N, int relu){
  __shared__ unsigned short As[64][256];
  __shared__ unsigned short Bs[64][256];
  int n0 = blockIdx.x*64, m0 = blockIdx.y*64;
  const unsigned short* Asrc = (A2 && n0 >= ncut) ? A2 : A;
  int t = threadIdx.x, wave = t>>6, lane = t&63;
  int wm = (wave>>1)*32, wn = (wave&1)*32;
  int hi = lane>>4, lo = lane&15;
  int lrow2 = lane>>5, lslot = lane&31;
  f32x4 acc[2][2];
#pragma unroll
  for(int i=0;i<2;++i)
#pragma unroll
    for(int j=0;j<2;++j)
#pragma unroll
      for(int r=0;r<4;++r) acc[i][j][r]=0.f;

  for(int k0=0;k0<K;k0+=256){
#pragma unroll
    for(int i=0;i<8;++i){
      int rt = wave*16 + 2*i + lrow2;          // tile row this lane feeds
      int col = ((lslot ^ (rt&7)))*8;          // pre-swizzled source slot
      int ga = m0+rt; if(ga >= M) ga = M-1;
      GLOAD_LDS(Asrc + (size_t)ga*K + k0 + col, &As[wave*16 + 2*i][0]);
      GLOAD_LDS(Bt + (size_t)(n0+rt)*K + k0 + col, &Bs[wave*16 + 2*i][0]);
    }
    __syncthreads();
#pragma unroll
    for(int kk=0;kk<8;++kk){
      int ps = (((kk*4+hi) ^ (lo&7)))*8;       // physical slot (elements)
      short8v a0 = *(short8v*)&As[wm+lo][ps];
      short8v a1 = *(short8v*)&As[wm+16+lo][ps];
      short8v b0 = *(short8v*)&Bs[wn+lo][ps];
      short8v b1 = *(short8v*)&Bs[wn+16+lo][ps];
      acc[0][0] = __builtin_amdgcn_mfma_f32_16x16x32_bf16(a0,b0,acc[0][0],0,0,0);
      acc[0][1] = __builtin_amdgcn_mfma_f32_16x16x32_bf16(a0,b1,acc[0][1],0,0,0);
      acc[1][0] = __builtin_amdgcn_mfma_f32_16x16x32_bf16(a1,b0,acc[1][0],0,0,0);
      acc[1][1] = __builtin_amdgcn_mfma_f32_16x16x32_bf16(a1,b1,acc[1][1],0,0,0);
    }
    if(k0 + 256 < K) __syncthreads();
  }
#pragma unroll
  for(int mf=0;mf<2;++mf){
#pragma unroll
    for(int nf=0;nf<2;++nf){
      int col = n0 + wn + nf*16 + lo;
      float bv = bias[col];
#pragma unroll
      for(int r=0;r<4;++r){
        int row = m0 + wm + mf*16 + hi*4 + r;
        if(row < M){
          float v = acc[mf][nf][r] + bv;
          if(relu) v = fmaxf(v, 0.f);
          if(Cf) Cf[(size_t)row*N+col] = v;
          if(Cb) Cb[(size_t)row*N+col] = f2bf(v);
        }
      }
    }
  }
}

// ------- bf16 MFMA value GEMM for ALL layers: [36864,256]@[256,1536] --------
// 3-buffer depth-2 pipeline with counted vmcnt across raw barriers (T3/T4)
__global__ __launch_bounds__(256) void mfma_value6(
    const unsigned short* __restrict__ Abf,   // [M][256] bf16
    const unsigned short* __restrict__ Bt,    // [1536][256] bf16 (all layers)
    const float* __restrict__ bias,           // [1536] (valb flat)
    const unsigned char* __restrict__ rowmask,
    unsigned short* __restrict__ C){          // [M][1536] bf16
  __shared__ unsigned short As[3][128][32];
  __shared__ unsigned short Bs[3][128][32];
  // bijective XCD swizzle: 3456 blocks = 8 x 432
  int id = blockIdx.x;
  int swz = (id & 7)*432 + (id >> 3);
  int m0 = (swz/12)*128, n0 = (swz%12)*128;
  int t = threadIdx.x;
  int wave = t>>6, lane = t&63;
  int wm = (wave>>1)*64, wn = (wave&1)*64;
  f32x4 acc[4][4];
#pragma unroll
  for(int i=0;i<4;++i)
#pragma unroll
    for(int j=0;j<4;++j)
#pragma unroll
      for(int r=0;r<4;++r) acc[i][j][r]=0.f;

  // pre-swizzled global column: phys slot (l&3) holds logical (l&3)^((row>>1)&3)
  int colx = ((lane&3) ^ ((lane>>3)&3)) * 8;
  const unsigned short* Ag = Abf + (size_t)(m0 + wave*32 + (lane>>2))*256 + colx;
  const unsigned short* Bg = Bt  + (size_t)(n0 + wave*32 + (lane>>2))*256 + colx;

  int hi = lane>>4, lo = lane&15;
  int sx = (hi ^ ((lo>>1)&3)) * 8;   // read-side physical slot (elements)

#define STAGE_V6(buf, kt) do{ \
    GLOAD_LDS(Ag + (kt)*32,          &As[buf][wave*32][0]);    \
    GLOAD_LDS(Ag + (kt)*32 + 16*256, &As[buf][wave*32+16][0]); \
    GLOAD_LDS(Bg + (kt)*32,          &Bs[buf][wave*32][0]);    \
    GLOAD_LDS(Bg + (kt)*32 + 16*256, &Bs[buf][wave*32+16][0]); \
  }while(0)

  // prologue: tiles 0,1 in flight; wait tile0 (vmcnt(4) leaves tile1's 4 pending)
  STAGE_V6(0, 0);
  STAGE_V6(1, 1);
  asm volatile("s_waitcnt vmcnt(4)" ::: "memory");
  __builtin_amdgcn_s_barrier();

#pragma unroll
  for(int k=0;k<8;++k){
    const int cur = k % 3;
    if(k < 6) STAGE_V6((k+2)%3, k+2);
    short8v a[4], bb[4];
#pragma unroll
    for(int mf=0;mf<4;++mf) a[mf]  = *(short8v*)&As[cur][wm+mf*16+lo][sx];
#pragma unroll
    for(int nf=0;nf<4;++nf) bb[nf] = *(short8v*)&Bs[cur][wn+nf*16+lo][sx];
#pragma unroll
    for(int mf=0;mf<4;++mf)
#pragma unroll
      for(int nf=0;nf<4;++nf)
        acc[mf][nf] = __builtin_amdgcn_mfma_f32_16x16x32_bf16(a[mf], bb[nf], acc[mf][nf], 0,0,0);
    if(k < 7){
      if(k < 6) asm volatile("s_waitcnt vmcnt(4)" ::: "memory");
      else      asm volatile("s_waitcnt vmcnt(0)" ::: "memory");
      __builtin_amdgcn_s_barrier();
    }
  }
#undef STAGE_V6

#pragma unroll
  for(int mf=0;mf<4;++mf){
    int rbase = m0 + wm + mf*16 + (lane>>4)*4;
#pragma unroll
    for(int nf=0;nf<4;++nf){
      int col = n0 + wn + nf*16 + (lane&15);
      float bv = bias[col];
#pragma unroll
      for(int r=0;r<4;++r){
        int row = rbase + r;
        float v = acc[mf][nf][r] + bv;
        if(rowmask[row]) v = 0.f;
        C[(size_t)row*VSTRIDE + col] = f2bf(v);
      }
    }
  }
}

// ---------------- MFMA self attention: block = (b,h) x 64-row Q tile --------
__global__ __launch_bounds__(256) void self_attn_mfma(
    const unsigned short* __restrict__ qkvh, // [1200][768] bf16 (q|k|v)
    unsigned short* __restrict__ sa){        // [1200][256] bf16
  __shared__ unsigned short P[64][328];
  __shared__ unsigned short Vt[32][328];
  int blk = blockIdx.x;
  int qt = blk % 5; int bh = blk / 5; int h = bh % NHD; int b = bh / NHD;
  int t = threadIdx.x, wv = t>>6, lane = t&63;
  int hi = lane>>4, lo = lane&15;
  {
    int c = t & 31, rb = t >> 5;
    for(int r = rb; r < 320; r += 8){
      unsigned short v = 0;
      if(r < 300) v = qkvh[(size_t)(b*300+r)*768 + 512 + h*32 + c];
      Vt[c][r] = v;
    }
  }
  __syncthreads();
  int m0 = qt*64 + wv*16;
  int qr = m0 + lo; if(qr > 299) qr = 299;
  short8v aq = *(const short8v*)(qkvh + (size_t)(b*300+qr)*768 + h*32 + hi*8);
  f32x4 s[19];
#pragma unroll
  for(int nt=0; nt<19; ++nt){
    int kr = nt*16 + lo; if(kr > 299) kr = 299;
    short8v bk = *(const short8v*)(qkvh + (size_t)(b*300+kr)*768 + 256 + h*32 + hi*8);
    f32x4 z; z[0]=0.f; z[1]=0.f; z[2]=0.f; z[3]=0.f;
    s[nt] = __builtin_amdgcn_mfma_f32_16x16x32_bf16(aq, bk, z, 0,0,0);
  }
  const float kSc = 0.25506009837f;   // (1/sqrt(32)) * log2(e)
  float inv[4];
#pragma unroll
  for(int ri=0; ri<4; ++ri){
    float m = -1e30f;
#pragma unroll
    for(int nt=0; nt<19; ++nt){
      if(nt*16+lo < 300) m = fmaxf(m, s[nt][ri]);
    }
#pragma unroll
    for(int o=8;o>=1;o>>=1) m = fmaxf(m, __shfl_xor(m,o,64));
    float sum = 0.f;
#pragma unroll
    for(int nt=0; nt<19; ++nt){
      float p = 0.f;
      if(nt*16+lo < 300) p = exp2f((s[nt][ri]-m)*kSc);
      sum += p;
      P[wv*16 + hi*4 + ri][nt*16 + lo] = f2bf(p);
    }
    P[wv*16 + hi*4 + ri][304 + lo] = 0;
#pragma unroll
    for(int o=8;o>=1;o>>=1) sum += __shfl_xor(sum,o,64);
    inv[ri] = 1.f/sum;
  }
  f32x4 o0, o1;
#pragma unroll
  for(int r=0;r<4;++r){ o0[r]=0.f; o1[r]=0.f; }
#pragma unroll
  for(int kt=0; kt<10; ++kt){
    short8v ap = *(short8v*)&P[wv*16 + lo][kt*32 + hi*8];
    short8v b0 = *(short8v*)&Vt[lo][kt*32 + hi*8];
    short8v b1 = *(short8v*)&Vt[16+lo][kt*32 + hi*8];
    o0 = __builtin_amdgcn_mfma_f32_16x16x32_bf16(ap, b0, o0, 0,0,0);
    o1 = __builtin_amdgcn_mfma_f32_16x16x32_bf16(ap, b1, o1, 0,0,0);
  }
#pragma unroll
  for(int ri=0; ri<4; ++ri){
    int r = m0 + hi*4 + ri;
    if(r < 300){
      size_t base = (size_t)(b*300+r)*256 + h*32;
      sa[base + lo]      = f2bf(o0[ri]*inv[ri]);
      sa[base + 16 + lo] = f2bf(o1[ri]*inv[ri]);
    }
  }
}

// ------- residual + layernorm, one ROW per WAVE, float4 loads, no LDS -------
__global__ void residual_ln(const float* __restrict__ base, const float* __restrict__ delta,
                            const float* __restrict__ lw, const float* __restrict__ lb,
                            float* __restrict__ dstf, unsigned short* __restrict__ dstb,
                            unsigned short* __restrict__ dstp, const float* __restrict__ qe){
  int w = threadIdx.x >> 6, lane = threadIdx.x & 63;
  size_t row = (size_t)blockIdx.x*4 + w;
  float4 bv = ((const float4*)(base + row*D))[lane];
  float4 dv = ((const float4*)(delta + row*D))[lane];
  float4 v; v.x=bv.x+dv.x; v.y=bv.y+dv.y; v.z=bv.z+dv.z; v.w=bv.w+dv.w;
  float s = wred_sum(v.x+v.y+v.z+v.w);
  float mean = s * (1.f/D);
  float4 c; c.x=v.x-mean; c.y=v.y-mean; c.z=v.z-mean; c.w=v.w-mean;
  float vs = wred_sum(c.x*c.x + c.y*c.y + c.z*c.z + c.w*c.w);
  float inv = rsqrtf(vs*(1.f/D) + LNEPS);
  float4 wv = ((const float4*)lw)[lane];
  float4 lbv = ((const float4*)lb)[lane];
  float4 y; y.x=c.x*inv*wv.x+lbv.x; y.y=c.y*inv*wv.y+lbv.y;
  y.z=c.z*inv*wv.z+lbv.z; y.w=c.w*inv*wv.w+lbv.w;
  ((float4*)(dstf + row*D))[lane] = y;
  if(dstb){
    ushort4 o; o.x=f2bf(y.x); o.y=f2bf(y.y); o.z=f2bf(y.z); o.w=f2bf(y.w);
    ((ushort4*)(dstb + row*D))[lane] = o;
  }
  if(dstp){
    int q = (int)(row % NQ);
    float4 qv = ((const float4*)(qe + (size_t)q*2*D))[lane];
    ushort4 o; o.x=f2bf(y.x+qv.x); o.y=f2bf(y.y+qv.y);
    o.z=f2bf(y.z+qv.z); o.w=f2bf(y.w+qv.w);
    ((ushort4*)(dstp + row*D))[lane] = o;
  }
}

// ---- fused: residual+LN (post-saout) + deformable cross-attn ---------------
__global__ void deform_attn_ln(const float* __restrict__ base, const float* __restrict__ delta,
                               const float* __restrict__ lnw, const float* __restrict__ lnb,
                               float* __restrict__ outb,      // LN result written back
                               const float* __restrict__ qe,
                               const float* __restrict__ offw, const float* __restrict__ offb,
                               const float* __restrict__ attnw, const float* __restrict__ attnb,
                               const unsigned short* __restrict__ value, const float* __restrict__ refp,
                               const float* __restrict__ vr, const int* __restrict__ sshape,
                               unsigned short* __restrict__ ca){
  __shared__ float qrow[D];
  __shared__ float part[96][2];
  __shared__ float proj[96];
  __shared__ float red[4];
  int row = blockIdx.x; int b = row / NQ; int q = row % NQ;
  int t = threadIdx.x;
  // residual + LN (per-row, full row in block)
  float v = base[(size_t)row*D+t] + delta[(size_t)row*D+t];
  float mean = bred_sum(v, red) * (1.f/D);
  float c = v - mean;
  float var = bred_sum(c*c, red) * (1.f/D);
  float y = c * rsqrtf(var + LNEPS) * lnw[t] + lnb[t];
  outb[(size_t)row*D+t] = y;
  qrow[t] = y + qe[(size_t)q*2*D + t];
  __syncthreads();
  if(t < 192){
    int col = t >> 1, half = t & 1;
    float acc = 0.f;
    if(col < 64){
      const float* W = offw;
      for(int k=half*128; k<half*128+128; ++k) acc += qrow[k]*W[(size_t)k*64 + col];
    } else {
      const float* W = attnw; int cc = col-64;
      for(int k=half*128; k<half*128+128; ++k) acc += qrow[k]*W[(size_t)k*32 + cc];
    }
    part[col][half] = acc;
  }
  __syncthreads();
  if(t < 96) proj[t] = part[t][0] + part[t][1] + (t<64 ? offb[t] : attnb[t-64]);
  __syncthreads();

  int h = t>>5, hd = t&31;
  float Hf = (float)sshape[0], Wf = (float)sshape[1];
  int Ws = sshape[1];
  float rx = refp[q*2+0] * vr[b*2+0];
  float ry = refp[q*2+1] * vr[b*2+1];
  const float* lg = &proj[64 + h*4];
  float m = fmaxf(fmaxf(lg[0],lg[1]),fmaxf(lg[2],lg[3]));
  float e[4]; float esum=0.f;
#pragma unroll
  for(int p=0;p<4;++p){ e[p]=expf(lg[p]-m); esum+=e[p]; }
  float einv = 1.f/esum;
  const float* ofr = &proj[h*8];
  const unsigned short* vbase = value + ((size_t)b*NSRC)*VSTRIDE + h*HDIM + hd;
  float acc = 0.f;
#pragma unroll
  for(int p=0;p<NPTS;++p){
    float lx = rx + ofr[p*2+0]/Wf;
    float ly = ry + ofr[p*2+1]/Hf;
    float x = lx*Wf - 0.5f, y2 = ly*Hf - 0.5f;
    float x0 = floorf(x), y0 = floorf(y2);
    float wx = x-x0, wy = y2-y0;
    float sample = 0.f;
#pragma unroll
    for(int cy=0;cy<2;++cy){
#pragma unroll
      for(int cx=0;cx<2;++cx){
        float xi = x0+cx, yi = y0+cy;
        float wgt = (cx? wx : 1.f-wx) * (cy? wy : 1.f-wy);
        bool valid = (xi>=0.f)&&(xi<=Wf-1.f)&&(yi>=0.f)&&(yi<=Hf-1.f);
        if(valid){
          int idx = (int)fminf(fmaxf(yi,0.f),Hf-1.f)*Ws + (int)fminf(fmaxf(xi,0.f),Wf-1.f);
          sample += wgt * bf2f(vbase[(size_t)idx*VSTRIDE]);
        }
      }
    }
    acc += (e[p]*einv) * sample;
  }
  ca[(size_t)row*D + h*HDIM + hd] = f2bf(acc);
}

// ---------------- host ----------------
extern "C" void kernel_launch(void* const* d_in, const int* in_sizes, int n_in,
                              void* d_out, int out_size, void* d_ws, size_t ws_size,
                              hipStream_t stream){
  const float* aps=(const float*)d_in[0];
  const float* dvs=(const float*)d_in[1];
  const float* qe =(const float*)d_in[2];
  const float* vr =(const float*)d_in[3];
  const float* aps_w1=(const float*)d_in[4]; const float* aps_b1=(const float*)d_in[5];
  const float* aps_w2=(const float*)d_in[6]; const float* aps_b2=(const float*)d_in[7];
  const float* dvs_w1=(const float*)d_in[8]; const float* dvs_b1=(const float*)d_in[9];
  const float* dvs_w2=(const float*)d_in[10]; const float* dvs_b2=(const float*)d_in[11];
  const float* ref_w=(const float*)d_in[12]; const float* ref_b=(const float*)d_in[13];
  const float* saqkvw=(const float*)d_in[14]; const float* saqkvb=(const float*)d_in[15];
  const float* saoutw=(const float*)d_in[16]; const float* saoutb=(const float*)d_in[17];
  const float* offw=(const float*)d_in[18]; const float* offb=(const float*)d_in[19];
  const float* attnw=(const float*)d_in[20]; const float* attnb=(const float*)d_in[21];
  const float* valw=(const float*)d_in[22]; const float* valb=(const float*)d_in[23];
  const float* coutw=(const float*)d_in[24]; const float* coutb=(const float*)d_in[25];
  const float* ln1w=(const float*)d_in[26]; const float* ln1b=(const float*)d_in[27];
  const float* ln2w=(const float*)d_in[28]; const float* ln2b=(const float*)d_in[29];
  const float* ln3w=(const float*)d_in[30]; const float* ln3b=(const float*)d_in[31];
  const float* ffw1=(const float*)d_in[32]; const float* ffb1=(const float*)d_in[33];
  const float* ffw2=(const float*)d_in[34]; const float* ffb2=(const float*)d_in[35];
  const unsigned char* mask=(const unsigned char*)d_in[36];
  const int* sshape=(const int*)d_in[37];
  float* out = (float*)d_out;

  char* wsb = (char*)d_ws;
  size_t o = 0;
  unsigned short* srcb   = (unsigned short*)(wsb+o); o += (size_t)NVROWS*D*2;
  unsigned short* valT   = (unsigned short*)(wsb+o); o += (size_t)NLAY*D*D*2;
  unsigned short* qkvT   = (unsigned short*)(wsb+o); o += (size_t)NLAY*3*D*D*2;
  unsigned short* saoutT = (unsigned short*)(wsb+o); o += (size_t)NLAY*D*D*2;
  unsigned short* coutT  = (unsigned short*)(wsb+o); o += (size_t)NLAY*D*D*2;
  unsigned short* ff1T   = (unsigned short*)(wsb+o); o += (size_t)NLAY*D*FFD*2;
  unsigned short* ff2T   = (unsigned short*)(wsb+o); o += (size_t)NLAY*FFD*D*2;
  unsigned short* value  = (unsigned short*)(wsb+o); o += (size_t)NVROWS*VSTRIDE*2;
  float* pA    = (float*)(wsb+o); o += (size_t)BSZ*CCHK*D*4;
  float* pD    = (float*)(wsb+o); o += (size_t)BSZ*CCHK*D*4;
  float* s2    = (float*)(wsb+o); o += 2*BSZ*D*4;
  float* tA    = (float*)(wsb+o); o += BSZ*D*4;
  float* tD    = (float*)(wsb+o); o += BSZ*D*4;
  float* cAB   = (float*)(wsb+o); o += 16*4;
  float* refp  = (float*)(wsb+o); o += NQ*2*4;
  float* outb  = (float*)(wsb+o); o += (size_t)NROWS*D*4;
  float* tmpb  = (float*)(wsb+o); o += (size_t)NROWS*D*4;
  unsigned short* out_bf    = (unsigned short*)(wsb+o); o += (size_t)NROWS*D*2;
  unsigned short* outpos_bf = (unsigned short*)(wsb+o); o += (size_t)NROWS*D*2;
  unsigned short* qkvh_bf   = (unsigned short*)(wsb+o); o += (size_t)NROWS*3*D*2;
  unsigned short* sa_bf     = (unsigned short*)(wsb+o); o += (size_t)NROWS*D*2;
  unsigned short* ca_bf     = (unsigned short*)(wsb+o); o += (size_t)NROWS*D*2;
  unsigned short* ffh_bf    = (unsigned short*)(wsb+o); o += (size_t)NROWS*FFD*2;

  // ---- prologue
  colsum_partial<<<BSZ*CCHK,256,0,stream>>>(aps,dvs,pA,pD);
  gate_s2<<<2*BSZ,256,0,stream>>>(pA,pD,aps_w2,aps_b2,dvs_w2,dvs_b2,aps_b1,dvs_b1,s2,cAB);
  gate_t<<<512,256,0,stream>>>(aps_w1,dvs_w1,s2,tA,tD);
  gate_src<<<NVROWS/4,256,0,stream>>>(aps,dvs,tA,tD,cAB,srcb);
  wconv_all<<<5376,256,0,stream>>>(valw,saqkvw,saoutw,coutw,ffw1,ffw2,
                                   valT,qkvT,saoutT,coutT,ff1T,ff2T);
  init_out_ref<<<NQ,256,0,stream>>>(qe,ref_w,ref_b,outb,out_bf,outpos_bf,refp,out);
  mfma_value6<<<(NVROWS/128)*(VSTRIDE/128),256,0,stream>>>(srcb, valT, valb, mask, value);

  dim3 gqkv(12,19), g256(4,19), gffu(16,19);

  for(int l=0;l<NLAY;++l){
    const unsigned short* qkvTl = qkvT + (size_t)l*3*D*D;
    const float* bqkv = saqkvb + (size_t)l*3*D;
    // self attention: q,k from out+qpos, v from out — one fused GEMM (N=768)
    gemmb<<<gqkv,256,0,stream>>>(outpos_bf, out_bf, 512, qkvTl, bqkv,
                                 nullptr, qkvh_bf, NROWS, D, 3*D, 0);
    self_attn_mfma<<<BSZ*NHD*5,256,0,stream>>>(qkvh_bf, sa_bf);
    gemmb<<<g256,256,0,stream>>>(sa_bf, nullptr, 0, saoutT+(size_t)l*D*D, saoutb+(size_t)l*D,
                                 tmpb, nullptr, NROWS, D, D, 0);

    // fused: residual+LN(ln2) + deformable cross attention
    deform_attn_ln<<<NROWS,256,0,stream>>>(outb, tmpb, ln2w+(size_t)l*D, ln2b+(size_t)l*D,
                                           outb, qe,
                                           offw+(size_t)l*D*64, offb+(size_t)l*64,
                                           attnw+(size_t)l*D*32, attnb+(size_t)l*32,
                                           value + (size_t)l*D, refp, vr, sshape, ca_bf);
    gemmb<<<g256,256,0,stream>>>(ca_bf, nullptr, 0, coutT+(size_t)l*D*D, coutb+(size_t)l*D,
                                 tmpb, nullptr, NROWS, D, D, 0);
    residual_ln<<<NROWS/4,256,0,stream>>>(outb,tmpb,ln1w+(size_t)l*D,ln1b+(size_t)l*D,
                                          outb,out_bf,nullptr,qe);

    // FFN
    gemmb<<<gffu,256,0,stream>>>(out_bf, nullptr, 0, ff1T+(size_t)l*D*FFD, ffb1+(size_t)l*FFD,
                                 nullptr, ffh_bf, NROWS, D, FFD, 1);
    gemmb<<<g256,256,0,stream>>>(ffh_bf, nullptr, 0, ff2T+(size_t)l*FFD*D, ffb2+(size_t)l*D,
                                 tmpb, nullptr, NROWS, FFD, D, 0);
    if(l==NLAY-1)
      residual_ln<<<NROWS/4,256,0,stream>>>(outb,tmpb,ln3w+(size_t)l*D,ln3b+(size_t)l*D,
                                            out,nullptr,nullptr,qe);
    else
      residual_ln<<<NROWS/4,256,0,stream>>>(outb,tmpb,ln3w+(size_t)l*D,ln3b+(size_t)l*D,
                                            outb,out_bf,outpos_bf,qe);
  }
}

// Round 15
// 611.111 us; speedup vs baseline: 1.0174x; 1.0055x over previous
//
#include <hip/hip_runtime.h>
#include <math.h>

#define D 256
#define NHD 8
#define HDIM 32
#define NPTS 4
#define NLAY 6
#define FFD 1024
#define BSZ 4
#define NSRC 9216
#define NQ 300
#define NROWS (BSZ*NQ)      // 1200
#define NVROWS (BSZ*NSRC)   // 36864
#define CCHK 256            // colsum chunks per batch (36 rows each)
#define LAYSZ ((size_t)NVROWS*D)   // per-layer value size (layer-major)
#define LNEPS 1e-5f

typedef __attribute__((ext_vector_type(8))) short short8v;
typedef __attribute__((ext_vector_type(4))) float f32x4;

// async global->LDS, 16B per lane; dest = wave-uniform base + lane*16
#define GLOAD_LDS(g, l) __builtin_amdgcn_global_load_lds( \
    (const __attribute__((address_space(1))) void*)(g), \
    (__attribute__((address_space(3))) void*)(l), 16, 0, 0)

__device__ __forceinline__ unsigned short f2bf(float f){
  unsigned u = __float_as_uint(f);
  unsigned r = (u + 0x7FFFu + ((u>>16)&1u)) >> 16;
  return (unsigned short)r;
}
__device__ __forceinline__ float bf2f(unsigned short u){
  return __uint_as_float(((unsigned)u)<<16);
}

// ---------------- reduction helpers ----------------
__device__ __forceinline__ float wred_sum(float v){
#pragma unroll
  for(int o=32;o>=1;o>>=1) v += __shfl_xor(v,o,64);
  return v;
}
__device__ __forceinline__ float bred_sum(float v, float* s){
  v = wred_sum(v);
  int lane = threadIdx.x & 63, wid = threadIdx.x >> 6;
  if(lane==0) s[wid]=v;
  __syncthreads();
  float r = s[0]+s[1]+s[2]+s[3];
  __syncthreads();
  return r;
}

// ---------------- gating front-end ----------------
__global__ void colsum_partial(const float* __restrict__ aps, const float* __restrict__ dvs,
                               float* __restrict__ pA, float* __restrict__ pD){
  __shared__ float4 sA[4][64]; __shared__ float4 sD[4][64];
  int blk = blockIdx.x; int b = blk / CCHK; int c = blk % CCHK;
  int t = threadIdx.x; int cl = t & 63; int rg = t >> 6;
  const int rows = NSRC / CCHK;   // 36
  size_t base = ((size_t)b*NSRC + (size_t)c*rows)*D + cl*4;
  float4 sa = make_float4(0.f,0.f,0.f,0.f), sd = sa;
  for(int r=rg; r<rows; r+=4){
    float4 va = *(const float4*)(aps + base + (size_t)r*D);
    float4 vd = *(const float4*)(dvs + base + (size_t)r*D);
    sa.x+=va.x; sa.y+=va.y; sa.z+=va.z; sa.w+=va.w;
    sd.x+=vd.x; sd.y+=vd.y; sd.z+=vd.z; sd.w+=vd.w;
  }
  sA[rg][cl]=sa; sD[rg][cl]=sd;
  __syncthreads();
  if(t < 64){
    float4 r0=sA[0][t],r1=sA[1][t],r2=sA[2][t],r3=sA[3][t];
    float4 o; o.x=r0.x+r1.x+r2.x+r3.x; o.y=r0.y+r1.y+r2.y+r3.y;
    o.z=r0.z+r1.z+r2.z+r3.z; o.w=r0.w+r1.w+r2.w+r3.w;
    *(float4*)(pA + ((size_t)b*CCHK+c)*D + t*4) = o;
  } else if(t < 128){
    int u=t-64;
    float4 r0=sD[0][u],r1=sD[1][u],r2=sD[2][u],r3=sD[3][u];
    float4 o; o.x=r0.x+r1.x+r2.x+r3.x; o.y=r0.y+r1.y+r2.y+r3.y;
    o.z=r0.z+r1.z+r2.z+r3.z; o.w=r0.w+r1.w+r2.w+r3.w;
    *(float4*)(pD + ((size_t)b*CCHK+c)*D + u*4) = o;
  }
}

// s2 = colsum@W2 + N*b2 ; c = b1.s2   — one block per (b,modality)
__global__ void gate_s2(const float* __restrict__ pA, const float* __restrict__ pD,
                        const float* __restrict__ w2a, const float* __restrict__ b2a,
                        const float* __restrict__ w2d, const float* __restrict__ b2d,
                        const float* __restrict__ b1a, const float* __restrict__ b1d,
                        float* __restrict__ s2, float* __restrict__ cAB){
  __shared__ float sums[D]; __shared__ float red[4];
  int blk = blockIdx.x; int b = blk>>1; int mod = blk&1;
  int t = threadIdx.x;
  const float* pX = mod? pD : pA;
  const float* w2 = mod? w2d : w2a;
  const float* b2 = mod? b2d : b2a;
  const float* b1 = mod? b1d : b1a;
  float s=0.f;
  for(int c=0;c<CCHK;++c) s += pX[((size_t)b*CCHK+c)*D+t];
  sums[t]=s; __syncthreads();
  float v=0.f;
  for(int i=0;i<D;++i) v += sums[i]*w2[(size_t)i*D+t];
  v += (float)NSRC * b2[t];
  s2[(size_t)blk*D + t] = v;
  float c = bred_sum(b1[t]*v, red);
  if(t==0) cAB[mod*BSZ + b] = c;
}

// t = W1 @ s2 — one wave per output element (2048 waves)
__global__ void gate_t(const float* __restrict__ w1a, const float* __restrict__ w1d,
                       const float* __restrict__ s2,
                       float* __restrict__ tA, float* __restrict__ tD){
  int gw = blockIdx.x*4 + (threadIdx.x>>6);
  int lane = threadIdx.x & 63;
  int i = gw & 255; int bm = gw >> 8;      // bm = b*2+mod
  int mod = bm & 1, b = bm >> 1;
  const float* w1 = mod? w1d : w1a;
  const float* s2v = s2 + (size_t)bm*D;
  float4 wv = *(const float4*)(w1 + (size_t)i*D + lane*4);
  float4 sv = *(const float4*)(s2v + lane*4);
  float d = wv.x*sv.x + wv.y*sv.y + wv.z*sv.z + wv.w*sv.w;
  d = wred_sum(d);
  if(lane==0){
    if(mod) tD[b*D+i] = d; else tA[b*D+i] = d;
  }
}

// per-row gate softmax + fused src (emits bf16)
__global__ void gate_src(const float* __restrict__ aps, const float* __restrict__ dvs,
                         const float* __restrict__ tA, const float* __restrict__ tD,
                         const float* __restrict__ cAB, unsigned short* __restrict__ srcb){
  int w = threadIdx.x >> 6, lane = threadIdx.x & 63;
  size_t row = (size_t)blockIdx.x*4 + w;
  int b = (int)(row / NSRC);
  const float4* ap = (const float4*)(aps + row*D);
  const float4* dp = (const float4*)(dvs + row*D);
  const float4* tap = (const float4*)(tA + (size_t)b*D);
  const float4* tdp = (const float4*)(tD + (size_t)b*D);
  float4 a = ap[lane], dd = dp[lane], ta = tap[lane], td = tdp[lane];
  float ga = a.x*ta.x + a.y*ta.y + a.z*ta.z + a.w*ta.w;
  float gd = dd.x*td.x + dd.y*td.y + dd.z*td.z + dd.w*td.w;
  ga = (wred_sum(ga) + cAB[b]) * 0.0625f;       // 1/sqrt(256)
  gd = (wred_sum(gd) + cAB[BSZ+b]) * 0.0625f;
  float m = fmaxf(ga,gd);
  float ea = expf(ga-m), ed = expf(gd-m);
  float inv = 1.f/(ea+ed);
  float wa = ea*inv, wd = ed*inv;
  ushort4 o;
  o.x = f2bf(wa*a.x + wd*dd.x); o.y = f2bf(wa*a.y + wd*dd.y);
  o.z = f2bf(wa*a.z + wd*dd.z); o.w = f2bf(wa*a.w + wd*dd.w);
  ((ushort4*)(srcb + row*D))[lane] = o;
}

// all weight transpose+convert in one launch: Bt[l][n][k] = bf16(W[l][k][n])
__global__ void wconv_all(const float* __restrict__ valw, const float* __restrict__ saqkvw,
                          const float* __restrict__ saoutw, const float* __restrict__ coutw,
                          const float* __restrict__ ffw1, const float* __restrict__ ffw2,
                          unsigned short* __restrict__ valT, unsigned short* __restrict__ qkvT,
                          unsigned short* __restrict__ saoutT, unsigned short* __restrict__ coutT,
                          unsigned short* __restrict__ ff1T, unsigned short* __restrict__ ff2T){
  __shared__ float tile[32][33];
  int bid = blockIdx.x;
  const float* W; unsigned short* Bt; int K, N, rel;
  if(bid < 384)      { W=valw;   Bt=valT;   K=256;  N=256;  rel=bid; }
  else if(bid < 1536){ W=saqkvw; Bt=qkvT;   K=256;  N=768;  rel=bid-384; }
  else if(bid < 1920){ W=saoutw; Bt=saoutT; K=256;  N=256;  rel=bid-1536; }
  else if(bid < 2304){ W=coutw;  Bt=coutT;  K=256;  N=256;  rel=bid-1920; }
  else if(bid < 3840){ W=ffw1;   Bt=ff1T;   K=256;  N=1024; rel=bid-2304; }
  else               { W=ffw2;   Bt=ff2T;   K=1024; N=256;  rel=bid-3840; }
  int nk = K>>5, nn = N>>5, tpl = nk*nn;
  int l = rel/tpl, rem = rel%tpl;
  int tk = rem % nk, tn = rem / nk;
  int tx = threadIdx.x & 31, ty = threadIdx.x >> 5;
  const float* Wl = W + (size_t)l*K*N;
  unsigned short* Btl = Bt + (size_t)l*N*K;
#pragma unroll
  for(int i=0;i<4;++i)
    tile[ty+i*8][tx] = Wl[(size_t)(tk*32+ty+i*8)*N + tn*32+tx];
  __syncthreads();
#pragma unroll
  for(int i=0;i<4;++i)
    Btl[(size_t)(tn*32+ty+i*8)*K + tk*32+tx] = f2bf(tile[tx][ty+i*8]);
}

__global__ void init_out_ref(const float* __restrict__ qe, const float* __restrict__ refw,
                             const float* __restrict__ refb,
                             float* __restrict__ outb, unsigned short* __restrict__ out_bf,
                             unsigned short* __restrict__ outpos_bf,
                             float* __restrict__ refp, float* __restrict__ dout){
  __shared__ float red[4];
  int q = blockIdx.x, t = threadIdx.x;
  float pos = qe[(size_t)q*2*D + t];
  float tgt = qe[(size_t)q*2*D + D + t];
  unsigned short tb = f2bf(tgt), tpb = f2bf(tgt+pos);
  for(int b=0;b<BSZ;++b){
    outb[((size_t)b*NQ+q)*D + t] = tgt;
    out_bf[((size_t)b*NQ+q)*D + t] = tb;
    outpos_bf[((size_t)b*NQ+q)*D + t] = tpb;
  }
  float d0 = bred_sum(pos*refw[t*2+0], red);
  float d1 = bred_sum(pos*refw[t*2+1], red);
  if(t<2){
    float dot = (t==0? d0 : d1) + refb[t];
    float r = 1.f/(1.f+expf(-dot));
    refp[q*2+t] = r;
    const size_t o1 = (size_t)BSZ*NQ*D;
    const size_t o2 = o1 + (size_t)BSZ*NQ*2;
    for(int b=0;b<BSZ;++b){
      dout[o1 + (b*NQ+q)*2 + t] = r;
      dout[o2 + (b*NQ+q)*2 + t] = r;
    }
  }
}

// ---- unified bf16 MFMA GEMM (M-chain), 64x64 tile, FULL-K (BK=256) staging --
__global__ __launch_bounds__(256) void gemmb(
    const unsigned short* __restrict__ A,   // [M][K] bf16
    const unsigned short* __restrict__ A2,
    int ncut,
    const unsigned short* __restrict__ Bt,  // [N][K] bf16
    const float* __restrict__ bias,
    float* __restrict__ Cf, unsigned short* __restrict__ Cb,
    int M, int K, int N, int relu){
  __shared__ unsigned short As[64][256];
  __shared__ unsigned short Bs[64][256];
  int n0 = blockIdx.x*64, m0 = blockIdx.y*64;
  const unsigned short* Asrc = (A2 && n0 >= ncut) ? A2 : A;
  int t = threadIdx.x, wave = t>>6, lane = t&63;
  int wm = (wave>>1)*32, wn = (wave&1)*32;
  int hi = lane>>4, lo = lane&15;
  int lrow2 = lane>>5, lslot = lane&31;
  f32x4 acc[2][2];
#pragma unroll
  for(int i=0;i<2;++i)
#pragma unroll
    for(int j=0;j<2;++j)
#pragma unroll
      for(int r=0;r<4;++r) acc[i][j][r]=0.f;

  for(int k0=0;k0<K;k0+=256){
#pragma unroll
    for(int i=0;i<8;++i){
      int rt = wave*16 + 2*i + lrow2;          // tile row this lane feeds
      int col = ((lslot ^ (rt&7)))*8;          // pre-swizzled source slot
      int ga = m0+rt; if(ga >= M) ga = M-1;
      GLOAD_LDS(Asrc + (size_t)ga*K + k0 + col, &As[wave*16 + 2*i][0]);
      GLOAD_LDS(Bt + (size_t)(n0+rt)*K + k0 + col, &Bs[wave*16 + 2*i][0]);
    }
    __syncthreads();
#pragma unroll
    for(int kk=0;kk<8;++kk){
      int ps = (((kk*4+hi) ^ (lo&7)))*8;       // physical slot (elements)
      short8v a0 = *(short8v*)&As[wm+lo][ps];
      short8v a1 = *(short8v*)&As[wm+16+lo][ps];
      short8v b0 = *(short8v*)&Bs[wn+lo][ps];
      short8v b1 = *(short8v*)&Bs[wn+16+lo][ps];
      acc[0][0] = __builtin_amdgcn_mfma_f32_16x16x32_bf16(a0,b0,acc[0][0],0,0,0);
      acc[0][1] = __builtin_amdgcn_mfma_f32_16x16x32_bf16(a0,b1,acc[0][1],0,0,0);
      acc[1][0] = __builtin_amdgcn_mfma_f32_16x16x32_bf16(a1,b0,acc[1][0],0,0,0);
      acc[1][1] = __builtin_amdgcn_mfma_f32_16x16x32_bf16(a1,b1,acc[1][1],0,0,0);
    }
    if(k0 + 256 < K) __syncthreads();
  }
#pragma unroll
  for(int mf=0;mf<2;++mf){
#pragma unroll
    for(int nf=0;nf<2;++nf){
      int col = n0 + wn + nf*16 + lo;
      float bv = bias[col];
#pragma unroll
      for(int r=0;r<4;++r){
        int row = m0 + wm + mf*16 + hi*4 + r;
        if(row < M){
          float v = acc[mf][nf][r] + bv;
          if(relu) v = fmaxf(v, 0.f);
          if(Cf) Cf[(size_t)row*N+col] = v;
          if(Cb) Cb[(size_t)row*N+col] = f2bf(v);
        }
      }
    }
  }
}

// ------- bf16 MFMA value GEMM for ALL layers, LAYER-MAJOR output ------------
// C[l][row][256]; writes have 512B row stride (4 rows/DRAM page)
__global__ __launch_bounds__(256) void mfma_value6(
    const unsigned short* __restrict__ Abf,   // [M][256] bf16
    const unsigned short* __restrict__ Bt,    // [1536][256] bf16 (all layers)
    const float* __restrict__ bias,           // [1536] (valb flat)
    const unsigned char* __restrict__ rowmask,
    unsigned short* __restrict__ C){          // [NLAY][M][256] bf16
  __shared__ unsigned short As[128][32];
  __shared__ unsigned short Bs[128][32];
  // bijective XCD swizzle: 3456 blocks = 8 x 432
  int id = blockIdx.x;
  int swz = (id & 7)*432 + (id >> 3);
  int m0 = (swz/12)*128, n0 = (swz%12)*128;
  int t = threadIdx.x;
  int wave = t>>6, lane = t&63;
  int wm = (wave>>1)*64, wn = (wave&1)*64;
  f32x4 acc[4][4];
#pragma unroll
  for(int i=0;i<4;++i)
#pragma unroll
    for(int j=0;j<4;++j)
#pragma unroll
      for(int r=0;r<4;++r) acc[i][j][r]=0.f;

  // pre-swizzled global column: phys slot (l&3) holds logical (l&3)^((row>>1)&3)
  int colx = ((lane&3) ^ ((lane>>3)&3)) * 8;
  const unsigned short* Ag = Abf + (size_t)(m0 + wave*32 + (lane>>2))*256 + colx;
  const unsigned short* Bg = Bt  + (size_t)(n0 + wave*32 + (lane>>2))*256 + colx;
  unsigned short* Al0 = &As[wave*32][0];
  unsigned short* Al1 = &As[wave*32+16][0];
  unsigned short* Bl0 = &Bs[wave*32][0];
  unsigned short* Bl1 = &Bs[wave*32+16][0];

  int hi = lane>>4, lo = lane&15;
  int sx = (hi ^ ((lo>>1)&3)) * 8;   // read-side physical slot (elements)

  for(int k0=0;k0<256;k0+=32){
    GLOAD_LDS(Ag + k0,           Al0);
    GLOAD_LDS(Ag + k0 + 16*256,  Al1);
    GLOAD_LDS(Bg + k0,           Bl0);
    GLOAD_LDS(Bg + k0 + 16*256,  Bl1);
    __syncthreads();
    short8v a[4], bb[4];
#pragma unroll
    for(int mf=0;mf<4;++mf) a[mf]  = *(short8v*)&As[wm+mf*16+lo][sx];
#pragma unroll
    for(int nf=0;nf<4;++nf) bb[nf] = *(short8v*)&Bs[wn+nf*16+lo][sx];
#pragma unroll
    for(int mf=0;mf<4;++mf)
#pragma unroll
      for(int nf=0;nf<4;++nf)
        acc[mf][nf] = __builtin_amdgcn_mfma_f32_16x16x32_bf16(a[mf], bb[nf], acc[mf][nf], 0,0,0);
    __syncthreads();
  }
  // epilogue: layer-major write. Tile never straddles a layer boundary.
  int lay = n0 >> 8;                // n0 in {0,128,...}: layer = n0/256
  int c0l = n0 & 255;               // column base within layer
  unsigned short* Cl = C + (size_t)lay*LAYSZ;
#pragma unroll
  for(int mf=0;mf<4;++mf){
    int rbase = m0 + wm + mf*16 + (lane>>4)*4;
#pragma unroll
    for(int nf=0;nf<4;++nf){
      int col = c0l + wn + nf*16 + (lane&15);
      float bv = bias[n0 + wn + nf*16 + (lane&15)];
#pragma unroll
      for(int r=0;r<4;++r){
        int row = rbase + r;
        float v = acc[mf][nf][r] + bv;
        if(rowmask[row]) v = 0.f;
        Cl[(size_t)row*D + col] = f2bf(v);
      }
    }
  }
}

// ---------------- MFMA self attention: block = (b,h) x 64-row Q tile --------
__global__ __launch_bounds__(256) void self_attn_mfma(
    const unsigned short* __restrict__ qkvh, // [1200][768] bf16 (q|k|v)
    unsigned short* __restrict__ sa){        // [1200][256] bf16
  __shared__ unsigned short P[64][328];
  __shared__ unsigned short Vt[32][328];
  int blk = blockIdx.x;
  int qt = blk % 5; int bh = blk / 5; int h = bh % NHD; int b = bh / NHD;
  int t = threadIdx.x, wv = t>>6, lane = t&63;
  int hi = lane>>4, lo = lane&15;
  {
    int c = t & 31, rb = t >> 5;
    for(int r = rb; r < 320; r += 8){
      unsigned short v = 0;
      if(r < 300) v = qkvh[(size_t)(b*300+r)*768 + 512 + h*32 + c];
      Vt[c][r] = v;
    }
  }
  __syncthreads();
  int m0 = qt*64 + wv*16;
  int qr = m0 + lo; if(qr > 299) qr = 299;
  short8v aq = *(const short8v*)(qkvh + (size_t)(b*300+qr)*768 + h*32 + hi*8);
  f32x4 s[19];
#pragma unroll
  for(int nt=0; nt<19; ++nt){
    int kr = nt*16 + lo; if(kr > 299) kr = 299;
    short8v bk = *(const short8v*)(qkvh + (size_t)(b*300+kr)*768 + 256 + h*32 + hi*8);
    f32x4 z; z[0]=0.f; z[1]=0.f; z[2]=0.f; z[3]=0.f;
    s[nt] = __builtin_amdgcn_mfma_f32_16x16x32_bf16(aq, bk, z, 0,0,0);
  }
  const float kSc = 0.25506009837f;   // (1/sqrt(32)) * log2(e)
  float inv[4];
#pragma unroll
  for(int ri=0; ri<4; ++ri){
    float m = -1e30f;
#pragma unroll
    for(int nt=0; nt<19; ++nt){
      if(nt*16+lo < 300) m = fmaxf(m, s[nt][ri]);
    }
#pragma unroll
    for(int o=8;o>=1;o>>=1) m = fmaxf(m, __shfl_xor(m,o,64));
    float sum = 0.f;
#pragma unroll
    for(int nt=0; nt<19; ++nt){
      float p = 0.f;
      if(nt*16+lo < 300) p = exp2f((s[nt][ri]-m)*kSc);
      sum += p;
      P[wv*16 + hi*4 + ri][nt*16 + lo] = f2bf(p);
    }
    P[wv*16 + hi*4 + ri][304 + lo] = 0;
#pragma unroll
    for(int o=8;o>=1;o>>=1) sum += __shfl_xor(sum,o,64);
    inv[ri] = 1.f/sum;
  }
  f32x4 o0, o1;
#pragma unroll
  for(int r=0;r<4;++r){ o0[r]=0.f; o1[r]=0.f; }
#pragma unroll
  for(int kt=0; kt<10; ++kt){
    short8v ap = *(short8v*)&P[wv*16 + lo][kt*32 + hi*8];
    short8v b0 = *(short8v*)&Vt[lo][kt*32 + hi*8];
    short8v b1 = *(short8v*)&Vt[16+lo][kt*32 + hi*8];
    o0 = __builtin_amdgcn_mfma_f32_16x16x32_bf16(ap, b0, o0, 0,0,0);
    o1 = __builtin_amdgcn_mfma_f32_16x16x32_bf16(ap, b1, o1, 0,0,0);
  }
#pragma unroll
  for(int ri=0; ri<4; ++ri){
    int r = m0 + hi*4 + ri;
    if(r < 300){
      size_t base = (size_t)(b*300+r)*256 + h*32;
      sa[base + lo]      = f2bf(o0[ri]*inv[ri]);
      sa[base + 16 + lo] = f2bf(o1[ri]*inv[ri]);
    }
  }
}

// ------- residual + layernorm, one ROW per WAVE, float4 loads, no LDS -------
__global__ void residual_ln(const float* __restrict__ base, const float* __restrict__ delta,
                            const float* __restrict__ lw, const float* __restrict__ lb,
                            float* __restrict__ dstf, unsigned short* __restrict__ dstb,
                            unsigned short* __restrict__ dstp, const float* __restrict__ qe){
  int w = threadIdx.x >> 6, lane = threadIdx.x & 63;
  size_t row = (size_t)blockIdx.x*4 + w;
  float4 bv = ((const float4*)(base + row*D))[lane];
  float4 dv = ((const float4*)(delta + row*D))[lane];
  float4 v; v.x=bv.x+dv.x; v.y=bv.y+dv.y; v.z=bv.z+dv.z; v.w=bv.w+dv.w;
  float s = wred_sum(v.x+v.y+v.z+v.w);
  float mean = s * (1.f/D);
  float4 c; c.x=v.x-mean; c.y=v.y-mean; c.z=v.z-mean; c.w=v.w-mean;
  float vs = wred_sum(c.x*c.x + c.y*c.y + c.z*c.z + c.w*c.w);
  float inv = rsqrtf(vs*(1.f/D) + LNEPS);
  float4 wv = ((const float4*)lw)[lane];
  float4 lbv = ((const float4*)lb)[lane];
  float4 y; y.x=c.x*inv*wv.x+lbv.x; y.y=c.y*inv*wv.y+lbv.y;
  y.z=c.z*inv*wv.z+lbv.z; y.w=c.w*inv*wv.w+lbv.w;
  ((float4*)(dstf + row*D))[lane] = y;
  if(dstb){
    ushort4 o; o.x=f2bf(y.x); o.y=f2bf(y.y); o.z=f2bf(y.z); o.w=f2bf(y.w);
    ((ushort4*)(dstb + row*D))[lane] = o;
  }
  if(dstp){
    int q = (int)(row % NQ);
    float4 qv = ((const float4*)(qe + (size_t)q*2*D))[lane];
    ushort4 o; o.x=f2bf(y.x+qv.x); o.y=f2bf(y.y+qv.y);
    o.z=f2bf(y.z+qv.z); o.w=f2bf(y.w+qv.w);
    ((ushort4*)(dstp + row*D))[lane] = o;
  }
}

// ---- fused: residual+LN (post-saout) + deformable cross-attn ---------------
__global__ void deform_attn_ln(const float* __restrict__ base, const float* __restrict__ delta,
                               const float* __restrict__ lnw, const float* __restrict__ lnb,
                               float* __restrict__ outb,      // LN result written back
                               const float* __restrict__ qe,
                               const float* __restrict__ offw, const float* __restrict__ offb,
                               const float* __restrict__ attnw, const float* __restrict__ attnb,
                               const unsigned short* __restrict__ value, const float* __restrict__ refp,
                               const float* __restrict__ vr, const int* __restrict__ sshape,
                               unsigned short* __restrict__ ca){
  __shared__ float qrow[D];
  __shared__ float part[96][2];
  __shared__ float proj[96];
  __shared__ float red[4];
  int row = blockIdx.x; int b = row / NQ; int q = row % NQ;
  int t = threadIdx.x;
  // residual + LN (per-row, full row in block)
  float v = base[(size_t)row*D+t] + delta[(size_t)row*D+t];
  float mean = bred_sum(v, red) * (1.f/D);
  float c = v - mean;
  float var = bred_sum(c*c, red) * (1.f/D);
  float y = c * rsqrtf(var + LNEPS) * lnw[t] + lnb[t];
  outb[(size_t)row*D+t] = y;
  qrow[t] = y + qe[(size_t)q*2*D + t];
  __syncthreads();
  if(t < 192){
    int col = t >> 1, half = t & 1;
    float acc = 0.f;
    if(col < 64){
      const float* W = offw;
      for(int k=half*128; k<half*128+128; ++k) acc += qrow[k]*W[(size_t)k*64 + col];
    } else {
      const float* W = attnw; int cc = col-64;
      for(int k=half*128; k<half*128+128; ++k) acc += qrow[k]*W[(size_t)k*32 + cc];
    }
    part[col][half] = acc;
  }
  __syncthreads();
  if(t < 96) proj[t] = part[t][0] + part[t][1] + (t<64 ? offb[t] : attnb[t-64]);
  __syncthreads();

  int h = t>>5, hd = t&31;
  float Hf = (float)sshape[0], Wf = (float)sshape[1];
  int Ws = sshape[1];
  float rx = refp[q*2+0] * vr[b*2+0];
  float ry = refp[q*2+1] * vr[b*2+1];
  const float* lg = &proj[64 + h*4];
  float m = fmaxf(fmaxf(lg[0],lg[1]),fmaxf(lg[2],lg[3]));
  float e[4]; float esum=0.f;
#pragma unroll
  for(int p=0;p<4;++p){ e[p]=expf(lg[p]-m); esum+=e[p]; }
  float einv = 1.f/esum;
  const float* ofr = &proj[h*8];
  const unsigned short* vbase = value + ((size_t)b*NSRC)*D + h*HDIM + hd;
  float acc = 0.f;
#pragma unroll
  for(int p=0;p<NPTS;++p){
    float lx = rx + ofr[p*2+0]/Wf;
    float ly = ry + ofr[p*2+1]/Hf;
    float x = lx*Wf - 0.5f, y2 = ly*Hf - 0.5f;
    float x0 = floorf(x), y0 = floorf(y2);
    float wx = x-x0, wy = y2-y0;
    float sample = 0.f;
#pragma unroll
    for(int cy=0;cy<2;++cy){
#pragma unroll
      for(int cx=0;cx<2;++cx){
        float xi = x0+cx, yi = y0+cy;
        float wgt = (cx? wx : 1.f-wx) * (cy? wy : 1.f-wy);
        bool valid = (xi>=0.f)&&(xi<=Wf-1.f)&&(yi>=0.f)&&(yi<=Hf-1.f);
        if(valid){
          int idx = (int)fminf(fmaxf(yi,0.f),Hf-1.f)*Ws + (int)fminf(fmaxf(xi,0.f),Wf-1.f);
          sample += wgt * bf2f(vbase[(size_t)idx*D]);
        }
      }
    }
    acc += (e[p]*einv) * sample;
  }
  ca[(size_t)row*D + h*HDIM + hd] = f2bf(acc);
}

// ---------------- host ----------------
extern "C" void kernel_launch(void* const* d_in, const int* in_sizes, int n_in,
                              void* d_out, int out_size, void* d_ws, size_t ws_size,
                              hipStream_t stream){
  const float* aps=(const float*)d_in[0];
  const float* dvs=(const float*)d_in[1];
  const float* qe =(const float*)d_in[2];
  const float* vr =(const float*)d_in[3];
  const float* aps_w1=(const float*)d_in[4]; const float* aps_b1=(const float*)d_in[5];
  const float* aps_w2=(const float*)d_in[6]; const float* aps_b2=(const float*)d_in[7];
  const float* dvs_w1=(const float*)d_in[8]; const float* dvs_b1=(const float*)d_in[9];
  const float* dvs_w2=(const float*)d_in[10]; const float* dvs_b2=(const float*)d_in[11];
  const float* ref_w=(const float*)d_in[12]; const float* ref_b=(const float*)d_in[13];
  const float* saqkvw=(const float*)d_in[14]; const float* saqkvb=(const float*)d_in[15];
  const float* saoutw=(const float*)d_in[16]; const float* saoutb=(const float*)d_in[17];
  const float* offw=(const float*)d_in[18]; const float* offb=(const float*)d_in[19];
  const float* attnw=(const float*)d_in[20]; const float* attnb=(const float*)d_in[21];
  const float* valw=(const float*)d_in[22]; const float* valb=(const float*)d_in[23];
  const float* coutw=(const float*)d_in[24]; const float* coutb=(const float*)d_in[25];
  const float* ln1w=(const float*)d_in[26]; const float* ln1b=(const float*)d_in[27];
  const float* ln2w=(const float*)d_in[28]; const float* ln2b=(const float*)d_in[29];
  const float* ln3w=(const float*)d_in[30]; const float* ln3b=(const float*)d_in[31];
  const float* ffw1=(const float*)d_in[32]; const float* ffb1=(const float*)d_in[33];
  const float* ffw2=(const float*)d_in[34]; const float* ffb2=(const float*)d_in[35];
  const unsigned char* mask=(const unsigned char*)d_in[36];
  const int* sshape=(const int*)d_in[37];
  float* out = (float*)d_out;

  char* wsb = (char*)d_ws;
  size_t o = 0;
  unsigned short* srcb   = (unsigned short*)(wsb+o); o += (size_t)NVROWS*D*2;
  unsigned short* valT   = (unsigned short*)(wsb+o); o += (size_t)NLAY*D*D*2;
  unsigned short* qkvT   = (unsigned short*)(wsb+o); o += (size_t)NLAY*3*D*D*2;
  unsigned short* saoutT = (unsigned short*)(wsb+o); o += (size_t)NLAY*D*D*2;
  unsigned short* coutT  = (unsigned short*)(wsb+o); o += (size_t)NLAY*D*D*2;
  unsigned short* ff1T   = (unsigned short*)(wsb+o); o += (size_t)NLAY*D*FFD*2;
  unsigned short* ff2T   = (unsigned short*)(wsb+o); o += (size_t)NLAY*FFD*D*2;
  unsigned short* value  = (unsigned short*)(wsb+o); o += (size_t)NLAY*NVROWS*D*2;
  float* pA    = (float*)(wsb+o); o += (size_t)BSZ*CCHK*D*4;
  float* pD    = (float*)(wsb+o); o += (size_t)BSZ*CCHK*D*4;
  float* s2    = (float*)(wsb+o); o += 2*BSZ*D*4;
  float* tA    = (float*)(wsb+o); o += BSZ*D*4;
  float* tD    = (float*)(wsb+o); o += BSZ*D*4;
  float* cAB   = (float*)(wsb+o); o += 16*4;
  float* refp  = (float*)(wsb+o); o += NQ*2*4;
  float* outb  = (float*)(wsb+o); o += (size_t)NROWS*D*4;
  float* tmpb  = (float*)(wsb+o); o += (size_t)NROWS*D*4;
  unsigned short* out_bf    = (unsigned short*)(wsb+o); o += (size_t)NROWS*D*2;
  unsigned short* outpos_bf = (unsigned short*)(wsb+o); o += (size_t)NROWS*D*2;
  unsigned short* qkvh_bf   = (unsigned short*)(wsb+o); o += (size_t)NROWS*3*D*2;
  unsigned short* sa_bf     = (unsigned short*)(wsb+o); o += (size_t)NROWS*D*2;
  unsigned short* ca_bf     = (unsigned short*)(wsb+o); o += (size_t)NROWS*D*2;
  unsigned short* ffh_bf    = (unsigned short*)(wsb+o); o += (size_t)NROWS*FFD*2;

  // ---- prologue
  colsum_partial<<<BSZ*CCHK,256,0,stream>>>(aps,dvs,pA,pD);
  gate_s2<<<2*BSZ,256,0,stream>>>(pA,pD,aps_w2,aps_b2,dvs_w2,dvs_b2,aps_b1,dvs_b1,s2,cAB);
  gate_t<<<512,256,0,stream>>>(aps_w1,dvs_w1,s2,tA,tD);
  gate_src<<<NVROWS/4,256,0,stream>>>(aps,dvs,tA,tD,cAB,srcb);
  wconv_all<<<5376,256,0,stream>>>(valw,saqkvw,saoutw,coutw,ffw1,ffw2,
                                   valT,qkvT,saoutT,coutT,ff1T,ff2T);
  init_out_ref<<<NQ,256,0,stream>>>(qe,ref_w,ref_b,outb,out_bf,outpos_bf,refp,out);
  mfma_value6<<<(NVROWS/128)*12,256,0,stream>>>(srcb, valT, valb, mask, value);

  dim3 gqkv(12,19), g256(4,19), gffu(16,19);

  for(int l=0;l<NLAY;++l){
    const unsigned short* qkvTl = qkvT + (size_t)l*3*D*D;
    const float* bqkv = saqkvb + (size_t)l*3*D;
    // self attention: q,k from out+qpos, v from out — one fused GEMM (N=768)
    gemmb<<<gqkv,256,0,stream>>>(outpos_bf, out_bf, 512, qkvTl, bqkv,
                                 nullptr, qkvh_bf, NROWS, D, 3*D, 0);
    self_attn_mfma<<<BSZ*NHD*5,256,0,stream>>>(qkvh_bf, sa_bf);
    gemmb<<<g256,256,0,stream>>>(sa_bf, nullptr, 0, saoutT+(size_t)l*D*D, saoutb+(size_t)l*D,
                                 tmpb, nullptr, NROWS, D, D, 0);

    // fused: residual+LN(ln2) + deformable cross attention (layer-major value)
    deform_attn_ln<<<NROWS,256,0,stream>>>(outb, tmpb, ln2w+(size_t)l*D, ln2b+(size_t)l*D,
                                           outb, qe,
                                           offw+(size_t)l*D*64, offb+(size_t)l*64,
                                           attnw+(size_t)l*D*32, attnb+(size_t)l*32,
                                           value + (size_t)l*LAYSZ, refp, vr, sshape, ca_bf);
    gemmb<<<g256,256,0,stream>>>(ca_bf, nullptr, 0, coutT+(size_t)l*D*D, coutb+(size_t)l*D,
                                 tmpb, nullptr, NROWS, D, D, 0);
    residual_ln<<<NROWS/4,256,0,stream>>>(outb,tmpb,ln1w+(size_t)l*D,ln1b+(size_t)l*D,
                                          outb,out_bf,nullptr,qe);

    // FFN
    gemmb<<<gffu,256,0,stream>>>(out_bf, nullptr, 0, ff1T+(size_t)l*D*FFD, ffb1+(size_t)l*FFD,
                                 nullptr, ffh_bf, NROWS, D, FFD, 1);
    gemmb<<<g256,256,0,stream>>>(ffh_bf, nullptr, 0, ff2T+(size_t)l*FFD*D, ffb2+(size_t)l*D,
                                 tmpb, nullptr, NROWS, FFD, D, 0);
    if(l==NLAY-1)
      residual_ln<<<NROWS/4,256,0,stream>>>(outb,tmpb,ln3w+(size_t)l*D,ln3b+(size_t)l*D,
                                            out,nullptr,nullptr,qe);
    else
      residual_ln<<<NROWS/4,256,0,stream>>>(outb,tmpb,ln3w+(size_t)l*D,ln3b+(size_t)l*D,
                                            outb,out_bf,outpos_bf,qe);
  }
}